// Round 1
// baseline (10416.361 us; speedup 1.0000x reference)
//
#include <hip/hip_runtime.h>
#include <math.h>

#define N_NODES 131072
#define NSTATES 64
#define SMOOTHK 12.0f

__device__ __forceinline__ float mishf(float x) {
    float e = expf(x);
    float sp = log1pf(e);          // softplus; overflows cleanly to +inf -> tanh=1
    return x * tanhf(sp);
}

// order-preserving f32 -> u32 encoding (0 reserved as "empty": only -NaN maps to 0)
__device__ __forceinline__ unsigned enc_f(float f) {
    unsigned u = __float_as_uint(f);
    return (u & 0x80000000u) ? ~u : (u | 0x80000000u);
}
__device__ __forceinline__ float dec_f(unsigned k) {
    unsigned u = (k & 0x80000000u) ? (k & 0x7fffffffu) : ~k;
    return __uint_as_float(u);
}

// ---------------------------------------------------------------------------
// Relation message kernel: x = gather(h)[m, AE]; y = x + mish(x@Wi+bi)@Wo+bo
// MODE 0: store y to ws + atomicMax seg_enc
// MODE 1: atomicMax seg_enc only (recompute path, pass 1)
// MODE 2: exp(12*(y-max)) + atomicAdd exps_sum (recompute path, pass 2)
// ---------------------------------------------------------------------------
template<int ARITY, int MODE>
__global__ __launch_bounds__(256) void rel_msg_kernel(
    const float* __restrict__ h, const int* __restrict__ atoms,
    const float* __restrict__ Wi, const float* __restrict__ bi,
    const float* __restrict__ Wo, const float* __restrict__ bo,
    float* __restrict__ y_ws, unsigned int* __restrict__ seg_enc,
    float* __restrict__ exps_sum, int m)
{
    constexpr int AE = ARITY * 64;
    constexpr int BA = 32;                  // atoms per block
    __shared__ __align__(16) float x_tile[BA * AE];
    __shared__ __align__(16) float t_tile[BA * AE];
    const int tid = threadIdx.x;
    const int a0 = blockIdx.x * BA;
    const float4* h4 = (const float4*)h;

    // stage gathered x rows (each row = concat of ARITY node embeddings)
    for (int t = tid; t < BA * (AE / 4); t += 256) {
        int a  = t / (AE / 4);
        int c4 = t % (AE / 4);
        int atom = a0 + a;
        float4 v = make_float4(0.f, 0.f, 0.f, 0.f);
        if (atom < m) {
            int node = atoms[atom * ARITY + (c4 >> 4)];
            v = h4[(size_t)node * 16 + (c4 & 15)];
        }
        ((float4*)x_tile)[a * (AE / 4) + c4] = v;
    }
    __syncthreads();

    const int lane  = tid & 63;
    const int abase = (tid >> 6) * 8;       // 8 atoms per wave

    // ---- matmul 1: inner = x @ Wi + bi ----
    float acc[ARITY][8];
    #pragma unroll
    for (int no = 0; no < ARITY; no++) {
        float b = bi[no * 64 + lane];
        #pragma unroll
        for (int a = 0; a < 8; a++) acc[no][a] = b;
    }
    for (int k0 = 0; k0 < AE; k0 += 4) {
        float4 xv[8];
        #pragma unroll
        for (int a = 0; a < 8; a++)
            xv[a] = *(const float4*)&x_tile[(abase + a) * AE + k0];
        #pragma unroll
        for (int kk = 0; kk < 4; kk++) {
            float wv[ARITY];
            #pragma unroll
            for (int no = 0; no < ARITY; no++)
                wv[no] = Wi[(k0 + kk) * AE + no * 64 + lane];
            #pragma unroll
            for (int a = 0; a < 8; a++) {
                float xa = (&xv[a].x)[kk];
                #pragma unroll
                for (int no = 0; no < ARITY; no++)
                    acc[no][a] = fmaf(xa, wv[no], acc[no][a]);
            }
        }
    }
    #pragma unroll
    for (int no = 0; no < ARITY; no++)
        #pragma unroll
        for (int a = 0; a < 8; a++)
            t_tile[(abase + a) * AE + no * 64 + lane] = mishf(acc[no][a]);
    __syncthreads();

    // ---- matmul 2: out = t @ Wo + bo ----
    float acc2[ARITY][8];
    #pragma unroll
    for (int no = 0; no < ARITY; no++) {
        float b = bo[no * 64 + lane];
        #pragma unroll
        for (int a = 0; a < 8; a++) acc2[no][a] = b;
    }
    for (int k0 = 0; k0 < AE; k0 += 4) {
        float4 tv[8];
        #pragma unroll
        for (int a = 0; a < 8; a++)
            tv[a] = *(const float4*)&t_tile[(abase + a) * AE + k0];
        #pragma unroll
        for (int kk = 0; kk < 4; kk++) {
            float wv[ARITY];
            #pragma unroll
            for (int no = 0; no < ARITY; no++)
                wv[no] = Wo[(k0 + kk) * AE + no * 64 + lane];
            #pragma unroll
            for (int a = 0; a < 8; a++) {
                float ta = (&tv[a].x)[kk];
                #pragma unroll
                for (int no = 0; no < ARITY; no++)
                    acc2[no][a] = fmaf(ta, wv[no], acc2[no][a]);
            }
        }
    }

    // ---- epilogue: residual + scatter ----
    #pragma unroll
    for (int no = 0; no < ARITY; no++) {
        #pragma unroll
        for (int a = 0; a < 8; a++) {
            int atom = a0 + abase + a;
            if (atom >= m) continue;
            float x = x_tile[(abase + a) * AE + no * 64 + lane];
            float y = x + acc2[no][a];
            int row  = atom * ARITY + no;
            int node = atoms[row];
            size_t cell = (size_t)node * 64 + lane;
            if (MODE == 0) {
                y_ws[(size_t)row * 64 + lane] = y;
                atomicMax(&seg_enc[cell], enc_f(y));
            } else if (MODE == 1) {
                atomicMax(&seg_enc[cell], enc_f(y));
            } else {
                float mx = dec_f(seg_enc[cell]);
                atomicAdd(&exps_sum[cell], expf(SMOOTHK * (y - mx)));
            }
        }
    }
}

// pass B when messages were stored: exp + scatter-add
__global__ __launch_bounds__(256) void passB_kernel(
    const float* __restrict__ y_ws, const int* __restrict__ atoms,
    const unsigned int* __restrict__ seg_enc, float* __restrict__ exps_sum,
    int rows)
{
    int g = blockIdx.x * 256 + threadIdx.x;
    if (g >= rows * 64) return;
    int row = g >> 6, e = g & 63;
    int node = atoms[row];
    size_t cell = (size_t)node * 64 + e;
    float y  = y_ws[g];
    float mx = dec_f(seg_enc[cell]);
    atomicAdd(&exps_sum[cell], expf(SMOOTHK * (y - mx)));
}

// ---------------------------------------------------------------------------
// Node update: max_msg from seg buffers; hnew = h + mish([max_msg,h]@uWi+ubi)@uWo+ubo
// ---------------------------------------------------------------------------
__global__ __launch_bounds__(256) void update_kernel(
    const float* __restrict__ h_in, const unsigned int* __restrict__ seg_enc,
    const float* __restrict__ exps_sum,
    const float* __restrict__ uWi, const float* __restrict__ ubi,
    const float* __restrict__ uWo, const float* __restrict__ ubo,
    float* __restrict__ h_out)
{
    __shared__ __align__(16) float x_tile[32 * 128];
    __shared__ __align__(16) float t_tile[32 * 128];
    const int tid = threadIdx.x;
    const int n0  = blockIdx.x * 32;

    for (int t = tid; t < 32 * 128; t += 256) {
        int a = t >> 7, c = t & 127;
        int node = n0 + a;
        float v;
        if (c < 64) {
            size_t cell = (size_t)node * 64 + c;
            float s = exps_sum[cell];
            unsigned key = seg_enc[cell];
            float mx = (key == 0u) ? 0.f : dec_f(key);
            v = logf(1e-16f + s) * (1.0f / SMOOTHK) + mx;
        } else {
            v = h_in[(size_t)node * 64 + (c - 64)];
        }
        x_tile[t] = v;
    }
    __syncthreads();

    const int lane  = tid & 63;
    const int abase = (tid >> 6) * 8;

    float acc[2][8];
    #pragma unroll
    for (int no = 0; no < 2; no++) {
        float b = ubi[no * 64 + lane];
        #pragma unroll
        for (int a = 0; a < 8; a++) acc[no][a] = b;
    }
    for (int k0 = 0; k0 < 128; k0 += 4) {
        float4 xv[8];
        #pragma unroll
        for (int a = 0; a < 8; a++)
            xv[a] = *(const float4*)&x_tile[(abase + a) * 128 + k0];
        #pragma unroll
        for (int kk = 0; kk < 4; kk++) {
            float w0 = uWi[(k0 + kk) * 128 + lane];
            float w1 = uWi[(k0 + kk) * 128 + 64 + lane];
            #pragma unroll
            for (int a = 0; a < 8; a++) {
                float xa = (&xv[a].x)[kk];
                acc[0][a] = fmaf(xa, w0, acc[0][a]);
                acc[1][a] = fmaf(xa, w1, acc[1][a]);
            }
        }
    }
    #pragma unroll
    for (int no = 0; no < 2; no++)
        #pragma unroll
        for (int a = 0; a < 8; a++)
            t_tile[(abase + a) * 128 + no * 64 + lane] = mishf(acc[no][a]);
    __syncthreads();

    float acc2[8];
    {
        float b = ubo[lane];
        #pragma unroll
        for (int a = 0; a < 8; a++) acc2[a] = b;
    }
    for (int k0 = 0; k0 < 128; k0 += 4) {
        float4 tv[8];
        #pragma unroll
        for (int a = 0; a < 8; a++)
            tv[a] = *(const float4*)&t_tile[(abase + a) * 128 + k0];
        #pragma unroll
        for (int kk = 0; kk < 4; kk++) {
            float w = uWo[(k0 + kk) * 64 + lane];
            #pragma unroll
            for (int a = 0; a < 8; a++)
                acc2[a] = fmaf((&tv[a].x)[kk], w, acc2[a]);
        }
    }
    #pragma unroll
    for (int a = 0; a < 8; a++) {
        int node = n0 + abase + a;
        float hold = x_tile[(abase + a) * 128 + 64 + lane];
        h_out[(size_t)node * 64 + lane] = hold + acc2[a];
    }
}

// ---------------------------------------------------------------------------
// Readout
// ---------------------------------------------------------------------------
__global__ __launch_bounds__(256) void readout_sum_kernel(
    const float* __restrict__ h, const int* __restrict__ ts,
    float* __restrict__ agg)
{
    int s = blockIdx.x;
    int off = 0;
    for (int i = 0; i < s; i++) off += ts[i];
    int cnt = ts[s];
    int col = threadIdx.x & 63, rg = threadIdx.x >> 6;
    float acc = 0.f;
    for (int r = rg; r < cnt; r += 4)
        acc += h[(size_t)(off + r) * 64 + col];
    __shared__ float red[4][64];
    red[rg][col] = acc;
    __syncthreads();
    if (rg == 0)
        agg[s * 64 + col] = red[0][col] + red[1][col] + red[2][col] + red[3][col];
}

__global__ __launch_bounds__(64) void readout_mlp_kernel(
    const float* __restrict__ agg,
    const float* __restrict__ vWi, const float* __restrict__ vbi,
    const float* __restrict__ vWo, const float* __restrict__ vbo,
    const float* __restrict__ dWi, const float* __restrict__ dbi,
    const float* __restrict__ dWo, const float* __restrict__ dbo,
    float* __restrict__ out)
{
    int s = blockIdx.x;
    int lane = threadIdx.x;
    float accv = vbi[lane], accd = dbi[lane];
    for (int k = 0; k < 64; k++) {
        float a = agg[s * 64 + k];
        accv = fmaf(a, vWi[k * 64 + lane], accv);
        accd = fmaf(a, dWi[k * 64 + lane], accd);
    }
    float pv = mishf(accv) * vWo[lane];
    float pd = mishf(accd) * dWo[lane];
    #pragma unroll
    for (int o = 1; o < 64; o <<= 1) {
        pv += __shfl_xor(pv, o);
        pd += __shfl_xor(pd, o);
    }
    if (lane == 0) { out[s] = pv + vbo[0]; out[64 + s] = pd + dbo[0]; }
}

// ---------------------------------------------------------------------------
extern "C" void kernel_launch(void* const* d_in, const int* in_sizes, int n_in,
                              void* d_out, int out_size, void* d_ws, size_t ws_size,
                              hipStream_t stream)
{
    const float* h0   = (const float*)d_in[0];
    const int* atoms1 = (const int*)d_in[1];
    const int* atoms2 = (const int*)d_in[2];
    const int* atoms3 = (const int*)d_in[3];
    const int* tsizes = (const int*)d_in[4];
    const float* Wi1 = (const float*)d_in[5],  *bi1 = (const float*)d_in[6];
    const float* Wo1 = (const float*)d_in[7],  *bo1 = (const float*)d_in[8];
    const float* Wi2 = (const float*)d_in[9],  *bi2 = (const float*)d_in[10];
    const float* Wo2 = (const float*)d_in[11], *bo2 = (const float*)d_in[12];
    const float* Wi3 = (const float*)d_in[13], *bi3 = (const float*)d_in[14];
    const float* Wo3 = (const float*)d_in[15], *bo3 = (const float*)d_in[16];
    const float* uWi = (const float*)d_in[17], *ubi = (const float*)d_in[18];
    const float* uWo = (const float*)d_in[19], *ubo = (const float*)d_in[20];
    const float* vWi = (const float*)d_in[21], *vbi = (const float*)d_in[22];
    const float* vWo = (const float*)d_in[23], *vbo = (const float*)d_in[24];
    const float* dWi = (const float*)d_in[25], *dbi = (const float*)d_in[26];
    const float* dWo = (const float*)d_in[27], *dbo = (const float*)d_in[28];
    float* out = (float*)d_out;

    const int rows1 = in_sizes[1];            // m*a per relation
    const int rows2 = in_sizes[2];
    const int rows3 = in_sizes[3];
    const int m1 = rows1 / 1, m2 = rows2 / 2, m3 = rows3 / 3;

    const size_t NH = (size_t)N_NODES * 64;
    char* ws = (char*)d_ws;
    float* h1          = (float*)ws;                 ws += NH * 4;
    float* h2          = (float*)ws;                 ws += NH * 4;
    unsigned int* enc  = (unsigned int*)ws;          ws += NH * 4;
    float* exps        = (float*)ws;                 ws += NH * 4;   // contiguous with enc
    float* agg         = (float*)ws;                 ws += NSTATES * 64 * 4;
    float* y_all       = (float*)ws;
    size_t used        = (size_t)(ws - (char*)d_ws);
    size_t y_bytes     = (size_t)(rows1 + rows2 + rows3) * 64 * 4;
    const bool store_y = (used + y_bytes <= ws_size);

    float* y1 = y_all;
    float* y2 = y_all + (size_t)rows1 * 64;
    float* y3 = y_all + (size_t)(rows1 + rows2) * 64;

    const int g1 = (m1 + 31) / 32, g2 = (m2 + 31) / 32, g3 = (m3 + 31) / 32;

    for (int layer = 0; layer < 2; layer++) {
        const float* hin = (layer == 0) ? h0 : h1;
        float* hout      = (layer == 0) ? h1 : h2;

        hipMemsetAsync(enc, 0, NH * 4 * 2, stream);   // enc + exps

        if (store_y) {
            rel_msg_kernel<1, 0><<<g1, 256, 0, stream>>>(hin, atoms1, Wi1, bi1, Wo1, bo1, y1, enc, exps, m1);
            rel_msg_kernel<2, 0><<<g2, 256, 0, stream>>>(hin, atoms2, Wi2, bi2, Wo2, bo2, y2, enc, exps, m2);
            rel_msg_kernel<3, 0><<<g3, 256, 0, stream>>>(hin, atoms3, Wi3, bi3, Wo3, bo3, y3, enc, exps, m3);
            passB_kernel<<<(rows1 * 64 + 255) / 256, 256, 0, stream>>>(y1, atoms1, enc, exps, rows1);
            passB_kernel<<<(rows2 * 64 + 255) / 256, 256, 0, stream>>>(y2, atoms2, enc, exps, rows2);
            passB_kernel<<<(rows3 * 64 + 255) / 256, 256, 0, stream>>>(y3, atoms3, enc, exps, rows3);
        } else {
            rel_msg_kernel<1, 1><<<g1, 256, 0, stream>>>(hin, atoms1, Wi1, bi1, Wo1, bo1, nullptr, enc, exps, m1);
            rel_msg_kernel<2, 1><<<g2, 256, 0, stream>>>(hin, atoms2, Wi2, bi2, Wo2, bo2, nullptr, enc, exps, m2);
            rel_msg_kernel<3, 1><<<g3, 256, 0, stream>>>(hin, atoms3, Wi3, bi3, Wo3, bo3, nullptr, enc, exps, m3);
            rel_msg_kernel<1, 2><<<g1, 256, 0, stream>>>(hin, atoms1, Wi1, bi1, Wo1, bo1, nullptr, enc, exps, m1);
            rel_msg_kernel<2, 2><<<g2, 256, 0, stream>>>(hin, atoms2, Wi2, bi2, Wo2, bo2, nullptr, enc, exps, m2);
            rel_msg_kernel<3, 2><<<g3, 256, 0, stream>>>(hin, atoms3, Wi3, bi3, Wo3, bo3, nullptr, enc, exps, m3);
        }

        update_kernel<<<N_NODES / 32, 256, 0, stream>>>(hin, enc, exps, uWi, ubi, uWo, ubo, hout);
    }

    readout_sum_kernel<<<NSTATES, 256, 0, stream>>>(h2, tsizes, agg);
    readout_mlp_kernel<<<NSTATES, 64, 0, stream>>>(agg, vWi, vbi, vWo, vbo,
                                                   dWi, dbi, dWo, dbo, out);
}

// Round 3
// 2083.105 us; speedup vs baseline: 5.0004x; 5.0004x over previous
//
#include <hip/hip_runtime.h>
#include <math.h>

#define N_NODES 131072
#define NSTATES 64
#define NH ((size_t)N_NODES * 64)

typedef short bf16x8 __attribute__((ext_vector_type(8)));
typedef float f32x4 __attribute__((ext_vector_type(4)));

__device__ __forceinline__ ushort f2bf(float f) {
    unsigned u = __float_as_uint(f);
    return (ushort)((u + 0x7fffu + ((u >> 16) & 1u)) >> 16);
}
__device__ __forceinline__ float bf2f(ushort h) {
    return __uint_as_float(((unsigned)h) << 16);
}
// mish(x) = x*tanh(softplus(x)) = x*(t^2+2t)/(t^2+2t+2), t=e^x
__device__ __forceinline__ float mishf(float x) {
    if (x > 30.f) return x;
    float t = __builtin_amdgcn_exp2f(1.4426950408889634f * x);
    float r = t * t + 2.f * t;
    return x * r * __builtin_amdgcn_rcpf(r + 2.f);
}
// order-preserving f32 -> u32 (0 only for -NaN => usable as "empty" sentinel)
__device__ __forceinline__ unsigned enc_f(float f) {
    unsigned u = __float_as_uint(f);
    return (u & 0x80000000u) ? ~u : (u | 0x80000000u);
}
__device__ __forceinline__ float dec_f(unsigned k) {
    unsigned u = (k & 0x80000000u) ? (k & 0x7fffffffu) : ~k;
    return __uint_as_float(u);
}

__device__ __forceinline__ bf16x8 load_row8(const float* p) {
    const float4* q = (const float4*)p;
    float4 v0 = q[0], v1 = q[1];
    bf16x8 u;
    u[0] = (short)f2bf(v0.x); u[1] = (short)f2bf(v0.y);
    u[2] = (short)f2bf(v0.z); u[3] = (short)f2bf(v0.w);
    u[4] = (short)f2bf(v1.x); u[5] = (short)f2bf(v1.y);
    u[6] = (short)f2bf(v1.z); u[7] = (short)f2bf(v1.w);
    return u;
}
__device__ __forceinline__ bf16x8 load_row8(const ushort* p) {
    return *(const bf16x8*)p;
}
__device__ __forceinline__ float h_at(const float* h, size_t i) { return h[i]; }
__device__ __forceinline__ float h_at(const ushort* h, size_t i) { return bf2f(h[i]); }

// ---------------------------------------------------------------------------
// weight convert: W [K(in)][Nc(out)] f32 -> WT [Nc][K] bf16 (transposed)
// ---------------------------------------------------------------------------
__global__ __launch_bounds__(256) void wt_conv_kernel(
    const float* __restrict__ W, ushort* __restrict__ WT, int K, int Nc)
{
    int i = blockIdx.x * 256 + threadIdx.x;
    if (i >= K * Nc) return;
    int o = i / K, k = i % K;
    WT[(size_t)o * K + k] = f2bf(W[(size_t)k * Nc + o]);
}

// ---------------------------------------------------------------------------
// CSR build
// ---------------------------------------------------------------------------
__global__ __launch_bounds__(256) void count_kernel(
    const int* __restrict__ atoms, int T, unsigned* __restrict__ cnt)
{
    int i = blockIdx.x * 256 + threadIdx.x;
    if (i < T) atomicAdd(&cnt[atoms[i]], 1u);
}

__global__ __launch_bounds__(256) void scan1_kernel(
    const unsigned* __restrict__ cnt, unsigned* __restrict__ base,
    unsigned* __restrict__ totals)
{
    __shared__ unsigned sm[256];
    int t = threadIdx.x, blk = blockIdx.x;
    int i0 = blk * 512;
    unsigned a = cnt[i0 + 2 * t], bb = cnt[i0 + 2 * t + 1];
    unsigned p = a + bb;
    sm[t] = p;
    __syncthreads();
    for (int off = 1; off < 256; off <<= 1) {
        unsigned v = (t >= off) ? sm[t - off] : 0u;
        __syncthreads();
        sm[t] += v;
        __syncthreads();
    }
    unsigned incl = sm[t];
    base[i0 + 2 * t]     = incl - p;
    base[i0 + 2 * t + 1] = incl - p + a;
    if (t == 255) totals[blk] = sm[255];
}

__global__ __launch_bounds__(256) void scan2_kernel(
    unsigned* __restrict__ base, const unsigned* __restrict__ totals)
{
    __shared__ unsigned ps[4];
    int t = threadIdx.x, blk = blockIdx.x;
    int lane = t & 63, wv = t >> 6;
    unsigned v = (t < blk) ? totals[t] : 0u;
    #pragma unroll
    for (int o = 32; o >= 1; o >>= 1) v += (unsigned)__shfl_xor((int)v, o);
    if (lane == 0) ps[wv] = v;
    __syncthreads();
    unsigned off = ps[0] + ps[1] + ps[2] + ps[3];
    int i0 = blk * 512;
    base[i0 + 2 * t]     += off;
    base[i0 + 2 * t + 1] += off;
}

__global__ __launch_bounds__(256) void copy_pos_kernel(
    const unsigned* __restrict__ base, unsigned* __restrict__ pos)
{
    int i = blockIdx.x * 256 + threadIdx.x;
    if (i < N_NODES) pos[i] = base[i];
}

// ---------------------------------------------------------------------------
// Relation MLP (bf16 MFMA): y = x + mish(x@Wi+bi)@Wo+bo
// MODE 0: scatter rows to CSR slots (1 atomic per row)
// MODE 1: atomicMax enc        (fallback pass 1)
// MODE 2: atomicAdd exp-sum    (fallback pass 2)
// ---------------------------------------------------------------------------
template<int ARITY, int MODE, typename HT>
__global__ __launch_bounds__(256, (ARITY == 3) ? 3 : 4)
void rel_kernel(const HT* __restrict__ h, const int* __restrict__ atoms,
                const ushort* __restrict__ WiT, const float* __restrict__ bi,
                const ushort* __restrict__ WoT, const float* __restrict__ bo,
                unsigned* __restrict__ pos, ushort* __restrict__ y_sorted,
                unsigned* __restrict__ enc, float* __restrict__ exps, int m)
{
    constexpr int AE = ARITY * 64;
    constexpr int BM = 64;
    constexpr int NT = AE / 16;
    constexpr int S  = AE * 2;                 // LDS row stride bytes
    __shared__ __align__(16) ushort xs[BM * AE];
    __shared__ __align__(16) ushort ts[BM * AE];
    const int tid = threadIdx.x, lane = tid & 63, wv = tid >> 6;
    const int a0 = blockIdx.x * BM;

    // ---- stage gathered x rows -> bf16, XOR-swizzled ----
    for (int task = tid; task < BM * (AE / 8); task += 256) {
        int r  = task / (AE / 8);
        int c8 = task % (AE / 8);
        int atom = a0 + r;
        bf16x8 u = {0, 0, 0, 0, 0, 0, 0, 0};
        if (atom < m) {
            int node = atoms[atom * ARITY + (c8 >> 3)];
            u = load_row8(h + (size_t)node * 64 + (size_t)(c8 & 7) * 8);
        }
        *(bf16x8*)((char*)xs + r * S + ((c8 * 16) ^ ((r & 7) << 4))) = u;
    }
    __syncthreads();

    const int r0 = wv * 16;
    const int arow = r0 + (lane & 15);
    const int kgrp = (lane >> 4) * 8;
    const int ncol = lane & 15;

    // ---- matmul1: inner = x @ Wi + bi ----
    f32x4 acc[NT];
    #pragma unroll
    for (int nt = 0; nt < NT; nt++) {
        float b = bi[nt * 16 + ncol];
        acc[nt] = (f32x4){b, b, b, b};
    }
    for (int k0 = 0; k0 < AE; k0 += 32) {
        bf16x8 af = *(const bf16x8*)((char*)xs + arow * S + (((k0 + kgrp) * 2) ^ ((arow & 7) << 4)));
        #pragma unroll
        for (int nt = 0; nt < NT; nt++) {
            bf16x8 bfv = *(const bf16x8*)(WiT + (size_t)(nt * 16 + ncol) * AE + k0 + kgrp);
            acc[nt] = __builtin_amdgcn_mfma_f32_16x16x32_bf16(af, bfv, acc[nt], 0, 0, 0);
        }
    }
    // D layout: row=(lane>>4)*4+j, col=lane&15 (m89-verified)
    #pragma unroll
    for (int nt = 0; nt < NT; nt++) {
        #pragma unroll
        for (int j = 0; j < 4; j++) {
            int row = r0 + (lane >> 4) * 4 + j;
            int col = nt * 16 + ncol;
            *(ushort*)((char*)ts + row * S + ((col * 2) ^ ((row & 7) << 4))) = f2bf(mishf(acc[nt][j]));
        }
    }
    __syncthreads();

    // ---- matmul2: out = t @ Wo + bo ----
    #pragma unroll
    for (int nt = 0; nt < NT; nt++) {
        float b = bo[nt * 16 + ncol];
        acc[nt] = (f32x4){b, b, b, b};
    }
    for (int k0 = 0; k0 < AE; k0 += 32) {
        bf16x8 af = *(const bf16x8*)((char*)ts + arow * S + (((k0 + kgrp) * 2) ^ ((arow & 7) << 4)));
        #pragma unroll
        for (int nt = 0; nt < NT; nt++) {
            bf16x8 bfv = *(const bf16x8*)(WoT + (size_t)(nt * 16 + ncol) * AE + k0 + kgrp);
            acc[nt] = __builtin_amdgcn_mfma_f32_16x16x32_bf16(af, bfv, acc[nt], 0, 0, 0);
        }
    }
    // residual y = x + out -> back into xs (bf16)
    #pragma unroll
    for (int nt = 0; nt < NT; nt++) {
        #pragma unroll
        for (int j = 0; j < 4; j++) {
            int row = r0 + (lane >> 4) * 4 + j;
            int col = nt * 16 + ncol;
            ushort* xp = (ushort*)((char*)xs + row * S + ((col * 2) ^ ((row & 7) << 4)));
            *xp = f2bf(bf2f(*xp) + acc[nt][j]);
        }
    }
    __syncthreads();

    // ---- epilogue: per message row ----
    const int nrows = BM * ARITY;
    for (int rr = wv; rr < nrows; rr += 4) {
        int grow = a0 * ARITY + rr;
        if (grow >= m * ARITY) break;
        int node = atoms[grow];
        int r = rr / ARITY;
        int c = (rr % ARITY) * 64 + lane;
        ushort yu = *(ushort*)((char*)xs + r * S + ((c * 2) ^ ((r & 7) << 4)));
        if (MODE == 0) {
            unsigned slot = 0;
            if (lane == 0) slot = atomicAdd(&pos[node], 1u);
            slot = (unsigned)__shfl((int)slot, 0);
            y_sorted[(size_t)slot * 64 + lane] = yu;
        } else if (MODE == 1) {
            atomicMax(&enc[(size_t)node * 64 + lane], enc_f(bf2f(yu)));
        } else {
            size_t cell = (size_t)node * 64 + lane;
            float mx = dec_f(enc[cell]);
            atomicAdd(&exps[cell], __builtin_amdgcn_exp2f(17.312340490667562f * (bf2f(yu) - mx)));
        }
    }
}

// ---------------------------------------------------------------------------
// Per-node smooth-max over CSR-sorted messages (no atomics)
// ---------------------------------------------------------------------------
__global__ __launch_bounds__(256) void aggregate_kernel(
    const ushort* __restrict__ y_sorted, const unsigned* __restrict__ base,
    const unsigned* __restrict__ cnt, ushort* __restrict__ mm)
{
    int node = blockIdx.x * 4 + (threadIdx.x >> 6);
    int lane = threadIdx.x & 63;
    unsigned b = base[node], c = cnt[node];
    const ushort* p = y_sorted + (size_t)b * 64 + lane;
    float mx = -3.402823466e38f;
    for (unsigned j = 0; j < c; j++)
        mx = fmaxf(mx, bf2f(p[(size_t)j * 64]));
    float me = c ? mx : 0.f;
    float s = 0.f;
    for (unsigned j = 0; j < c; j++)
        s += __builtin_amdgcn_exp2f(17.312340490667562f * (bf2f(p[(size_t)j * 64]) - me));
    // ln(1e-16+s)/12 + me  (v_log is log2 -> scale by ln2/12)
    float r = __builtin_amdgcn_logf(1e-16f + s) * 0.05776226504666211f + me;
    mm[(size_t)node * 64 + lane] = f2bf(r);
}

// fallback finalize: mm from (enc, exps)
__global__ __launch_bounds__(256) void finalize_mm_kernel(
    const unsigned* __restrict__ enc, const float* __restrict__ exps,
    ushort* __restrict__ mm)
{
    size_t i = (size_t)blockIdx.x * 256 + threadIdx.x;
    if (i >= NH) return;
    unsigned key = enc[i];
    float mx = key ? dec_f(key) : 0.f;
    float r = __builtin_amdgcn_logf(1e-16f + exps[i]) * 0.05776226504666211f + mx;
    mm[i] = f2bf(r);
}

// ---------------------------------------------------------------------------
// Node update (bf16 MFMA): hnew = h + mish([max_msg,h]@uWi+ubi)@uWo+ubo
// hout is bf16; safe to run in-place when HT == ushort (block-local rows,
// each element read+written by the same thread after all staging reads).
// ---------------------------------------------------------------------------
template<typename HT>
__global__ __launch_bounds__(256, 4)
void update_kernel(const HT* __restrict__ hin, const ushort* __restrict__ mm,
                   const ushort* __restrict__ uWiT, const float* __restrict__ ubi,
                   const ushort* __restrict__ uWoT, const float* __restrict__ ubo,
                   ushort* __restrict__ hout)
{
    constexpr int AE = 128, BM = 64, S = 256, NT = 8, NT2 = 4;
    __shared__ __align__(16) ushort xs[BM * AE];
    __shared__ __align__(16) ushort ts[BM * AE];
    const int tid = threadIdx.x, lane = tid & 63, wv = tid >> 6;
    const int n0 = blockIdx.x * BM;

    for (int task = tid; task < BM * 16; task += 256) {
        int r = task >> 4, c8 = task & 15;
        int node = n0 + r;
        bf16x8 u;
        if (c8 < 8) u = *(const bf16x8*)(mm + (size_t)node * 64 + c8 * 8);
        else        u = load_row8(hin + (size_t)node * 64 + (size_t)(c8 - 8) * 8);
        *(bf16x8*)((char*)xs + r * S + ((c8 * 16) ^ ((r & 7) << 4))) = u;
    }
    __syncthreads();

    const int r0 = wv * 16;
    const int arow = r0 + (lane & 15);
    const int kgrp = (lane >> 4) * 8;
    const int ncol = lane & 15;

    f32x4 acc[NT];
    #pragma unroll
    for (int nt = 0; nt < NT; nt++) {
        float b = ubi[nt * 16 + ncol];
        acc[nt] = (f32x4){b, b, b, b};
    }
    for (int k0 = 0; k0 < AE; k0 += 32) {
        bf16x8 af = *(const bf16x8*)((char*)xs + arow * S + (((k0 + kgrp) * 2) ^ ((arow & 7) << 4)));
        #pragma unroll
        for (int nt = 0; nt < NT; nt++) {
            bf16x8 bfv = *(const bf16x8*)(uWiT + (size_t)(nt * 16 + ncol) * AE + k0 + kgrp);
            acc[nt] = __builtin_amdgcn_mfma_f32_16x16x32_bf16(af, bfv, acc[nt], 0, 0, 0);
        }
    }
    #pragma unroll
    for (int nt = 0; nt < NT; nt++) {
        #pragma unroll
        for (int j = 0; j < 4; j++) {
            int row = r0 + (lane >> 4) * 4 + j;
            int col = nt * 16 + ncol;
            *(ushort*)((char*)ts + row * S + ((col * 2) ^ ((row & 7) << 4))) = f2bf(mishf(acc[nt][j]));
        }
    }
    __syncthreads();

    f32x4 acc2[NT2];
    #pragma unroll
    for (int nt = 0; nt < NT2; nt++) {
        float b = ubo[nt * 16 + ncol];
        acc2[nt] = (f32x4){b, b, b, b};
    }
    for (int k0 = 0; k0 < AE; k0 += 32) {
        bf16x8 af = *(const bf16x8*)((char*)ts + arow * S + (((k0 + kgrp) * 2) ^ ((arow & 7) << 4)));
        #pragma unroll
        for (int nt = 0; nt < NT2; nt++) {
            bf16x8 bfv = *(const bf16x8*)(uWoT + (size_t)(nt * 16 + ncol) * 128 + k0 + kgrp);
            acc2[nt] = __builtin_amdgcn_mfma_f32_16x16x32_bf16(af, bfv, acc2[nt], 0, 0, 0);
        }
    }
    #pragma unroll
    for (int nt = 0; nt < NT2; nt++) {
        #pragma unroll
        for (int j = 0; j < 4; j++) {
            int row = r0 + (lane >> 4) * 4 + j;
            int col = nt * 16 + ncol;
            size_t gi = (size_t)(n0 + row) * 64 + col;
            hout[gi] = f2bf(h_at(hin, gi) + acc2[nt][j]);
        }
    }
}

// ---------------------------------------------------------------------------
// Readout
// ---------------------------------------------------------------------------
__global__ __launch_bounds__(256) void readout_sum_kernel(
    const ushort* __restrict__ h, const int* __restrict__ toksz,
    float* __restrict__ agg)
{
    int s = blockIdx.x;
    int off = 0;
    for (int i = 0; i < s; i++) off += toksz[i];
    int cntr = toksz[s];
    int col = threadIdx.x & 63, rg = threadIdx.x >> 6;
    float acc = 0.f;
    for (int r = rg; r < cntr; r += 4)
        acc += bf2f(h[(size_t)(off + r) * 64 + col]);
    __shared__ float red[4][64];
    red[rg][col] = acc;
    __syncthreads();
    if (rg == 0)
        agg[s * 64 + col] = red[0][col] + red[1][col] + red[2][col] + red[3][col];
}

__global__ __launch_bounds__(64) void readout_mlp_kernel(
    const float* __restrict__ agg,
    const float* __restrict__ vWi, const float* __restrict__ vbi,
    const float* __restrict__ vWo, const float* __restrict__ vbo,
    const float* __restrict__ dWi, const float* __restrict__ dbi,
    const float* __restrict__ dWo, const float* __restrict__ dbo,
    float* __restrict__ out)
{
    int s = blockIdx.x;
    int lane = threadIdx.x;
    float accv = vbi[lane], accd = dbi[lane];
    for (int k = 0; k < 64; k++) {
        float a = agg[s * 64 + k];
        accv = fmaf(a, vWi[k * 64 + lane], accv);
        accd = fmaf(a, dWi[k * 64 + lane], accd);
    }
    float pv = mishf(accv) * vWo[lane];
    float pd = mishf(accd) * dWo[lane];
    #pragma unroll
    for (int o = 1; o < 64; o <<= 1) {
        pv += __shfl_xor(pv, o);
        pd += __shfl_xor(pd, o);
    }
    if (lane == 0) { out[s] = pv + vbo[0]; out[64 + s] = pd + dbo[0]; }
}

// ---------------------------------------------------------------------------
extern "C" void kernel_launch(void* const* d_in, const int* in_sizes, int n_in,
                              void* d_out, int out_size, void* d_ws, size_t ws_size,
                              hipStream_t stream)
{
    const float* h0   = (const float*)d_in[0];
    const int* atoms1 = (const int*)d_in[1];
    const int* atoms2 = (const int*)d_in[2];
    const int* atoms3 = (const int*)d_in[3];
    const int* tsizes = (const int*)d_in[4];
    const float* Wi1 = (const float*)d_in[5],  *bi1 = (const float*)d_in[6];
    const float* Wo1 = (const float*)d_in[7],  *bo1 = (const float*)d_in[8];
    const float* Wi2 = (const float*)d_in[9],  *bi2 = (const float*)d_in[10];
    const float* Wo2 = (const float*)d_in[11], *bo2 = (const float*)d_in[12];
    const float* Wi3 = (const float*)d_in[13], *bi3 = (const float*)d_in[14];
    const float* Wo3 = (const float*)d_in[15], *bo3 = (const float*)d_in[16];
    const float* uWi = (const float*)d_in[17], *ubi = (const float*)d_in[18];
    const float* uWo = (const float*)d_in[19], *ubo = (const float*)d_in[20];
    const float* vWi = (const float*)d_in[21], *vbi = (const float*)d_in[22];
    const float* vWo = (const float*)d_in[23], *vbo = (const float*)d_in[24];
    const float* dWi = (const float*)d_in[25], *dbi = (const float*)d_in[26];
    const float* dWo = (const float*)d_in[27], *dbo = (const float*)d_in[28];
    float* out = (float*)d_out;

    const int rows1 = in_sizes[1];
    const int rows2 = in_sizes[2];
    const int rows3 = in_sizes[3];
    const int m1 = rows1, m2 = rows2 / 2, m3 = rows3 / 3;
    const int T = rows1 + rows2 + rows3;

    char* w = (char*)d_ws;
    auto alloc = [&](size_t bytes) { char* p = w; w += (bytes + 255) & ~(size_t)255; return p; };
    ushort* h1       = (ushort*)alloc(NH * 2);
    ushort* mm       = (ushort*)alloc(NH * 2);
    unsigned* cnt    = (unsigned*)alloc(N_NODES * 4);
    unsigned* base   = (unsigned*)alloc(N_NODES * 4);
    unsigned* pos    = (unsigned*)alloc(N_NODES * 4);
    unsigned* totals = (unsigned*)alloc(256 * 4);
    float* agg       = (float*)alloc(NSTATES * 64 * 4);
    ushort* WiT1 = (ushort*)alloc(64 * 64 * 2);
    ushort* WoT1 = (ushort*)alloc(64 * 64 * 2);
    ushort* WiT2 = (ushort*)alloc(128 * 128 * 2);
    ushort* WoT2 = (ushort*)alloc(128 * 128 * 2);
    ushort* WiT3 = (ushort*)alloc(192 * 192 * 2);
    ushort* WoT3 = (ushort*)alloc(192 * 192 * 2);
    ushort* uWiT = (ushort*)alloc(128 * 128 * 2);
    ushort* uWoT = (ushort*)alloc(64 * 128 * 2);
    char* tail = w;

    // primary (CSR) needs y_sorted; fallback needs enc+exps
    size_t y_bytes  = (size_t)T * 64 * 2;
    const bool csr  = ((size_t)(tail - (char*)d_ws) + ((y_bytes + 255) & ~(size_t)255)) <= ws_size;
    ushort* y_sorted = nullptr;
    unsigned* enc = nullptr;
    float* exps = nullptr;
    if (csr) {
        y_sorted = (ushort*)alloc(y_bytes);
    } else {
        enc  = (unsigned*)alloc(NH * 4);
        exps = (float*)alloc(NH * 4);        // contiguous with enc
    }

    // weight conversions (f32 -> bf16 transposed [out][in])
    wt_conv_kernel<<<(64 * 64 + 255) / 256, 256, 0, stream>>>(Wi1, WiT1, 64, 64);
    wt_conv_kernel<<<(64 * 64 + 255) / 256, 256, 0, stream>>>(Wo1, WoT1, 64, 64);
    wt_conv_kernel<<<(128 * 128 + 255) / 256, 256, 0, stream>>>(Wi2, WiT2, 128, 128);
    wt_conv_kernel<<<(128 * 128 + 255) / 256, 256, 0, stream>>>(Wo2, WoT2, 128, 128);
    wt_conv_kernel<<<(192 * 192 + 255) / 256, 256, 0, stream>>>(Wi3, WiT3, 192, 192);
    wt_conv_kernel<<<(192 * 192 + 255) / 256, 256, 0, stream>>>(Wo3, WoT3, 192, 192);
    wt_conv_kernel<<<(128 * 128 + 255) / 256, 256, 0, stream>>>(uWi, uWiT, 128, 128);
    wt_conv_kernel<<<(128 * 64 + 255) / 256, 256, 0, stream>>>(uWo, uWoT, 128, 64);

    if (csr) {
        hipMemsetAsync(cnt, 0, N_NODES * 4, stream);
        count_kernel<<<(rows1 + 255) / 256, 256, 0, stream>>>(atoms1, rows1, cnt);
        count_kernel<<<(rows2 + 255) / 256, 256, 0, stream>>>(atoms2, rows2, cnt);
        count_kernel<<<(rows3 + 255) / 256, 256, 0, stream>>>(atoms3, rows3, cnt);
        scan1_kernel<<<256, 256, 0, stream>>>(cnt, base, totals);
        scan2_kernel<<<256, 256, 0, stream>>>(base, totals);
    }

    const int g1 = (m1 + 63) / 64, g2 = (m2 + 63) / 64, g3 = (m3 + 63) / 64;

    for (int layer = 0; layer < 2; layer++) {
        if (csr) {
            copy_pos_kernel<<<(N_NODES + 255) / 256, 256, 0, stream>>>(base, pos);
            if (layer == 0) {
                rel_kernel<1, 0, float><<<g1, 256, 0, stream>>>(h0, atoms1, WiT1, bi1, WoT1, bo1, pos, y_sorted, nullptr, nullptr, m1);
                rel_kernel<2, 0, float><<<g2, 256, 0, stream>>>(h0, atoms2, WiT2, bi2, WoT2, bo2, pos, y_sorted, nullptr, nullptr, m2);
                rel_kernel<3, 0, float><<<g3, 256, 0, stream>>>(h0, atoms3, WiT3, bi3, WoT3, bo3, pos, y_sorted, nullptr, nullptr, m3);
            } else {
                rel_kernel<1, 0, ushort><<<g1, 256, 0, stream>>>(h1, atoms1, WiT1, bi1, WoT1, bo1, pos, y_sorted, nullptr, nullptr, m1);
                rel_kernel<2, 0, ushort><<<g2, 256, 0, stream>>>(h1, atoms2, WiT2, bi2, WoT2, bo2, pos, y_sorted, nullptr, nullptr, m2);
                rel_kernel<3, 0, ushort><<<g3, 256, 0, stream>>>(h1, atoms3, WiT3, bi3, WoT3, bo3, pos, y_sorted, nullptr, nullptr, m3);
            }
            aggregate_kernel<<<N_NODES / 4, 256, 0, stream>>>(y_sorted, base, cnt, mm);
        } else {
            hipMemsetAsync(enc, 0, NH * 8, stream);   // enc + exps
            if (layer == 0) {
                rel_kernel<1, 1, float><<<g1, 256, 0, stream>>>(h0, atoms1, WiT1, bi1, WoT1, bo1, nullptr, nullptr, enc, exps, m1);
                rel_kernel<2, 1, float><<<g2, 256, 0, stream>>>(h0, atoms2, WiT2, bi2, WoT2, bo2, nullptr, nullptr, enc, exps, m2);
                rel_kernel<3, 1, float><<<g3, 256, 0, stream>>>(h0, atoms3, WiT3, bi3, WoT3, bo3, nullptr, nullptr, enc, exps, m3);
                rel_kernel<1, 2, float><<<g1, 256, 0, stream>>>(h0, atoms1, WiT1, bi1, WoT1, bo1, nullptr, nullptr, enc, exps, m1);
                rel_kernel<2, 2, float><<<g2, 256, 0, stream>>>(h0, atoms2, WiT2, bi2, WoT2, bo2, nullptr, nullptr, enc, exps, m2);
                rel_kernel<3, 2, float><<<g3, 256, 0, stream>>>(h0, atoms3, WiT3, bi3, WoT3, bo3, nullptr, nullptr, enc, exps, m3);
            } else {
                rel_kernel<1, 1, ushort><<<g1, 256, 0, stream>>>(h1, atoms1, WiT1, bi1, WoT1, bo1, nullptr, nullptr, enc, exps, m1);
                rel_kernel<2, 1, ushort><<<g2, 256, 0, stream>>>(h1, atoms2, WiT2, bi2, WoT2, bo2, nullptr, nullptr, enc, exps, m2);
                rel_kernel<3, 1, ushort><<<g3, 256, 0, stream>>>(h1, atoms3, WiT3, bi3, WoT3, bo3, nullptr, nullptr, enc, exps, m3);
                rel_kernel<1, 2, ushort><<<g1, 256, 0, stream>>>(h1, atoms1, WiT1, bi1, WoT1, bo1, nullptr, nullptr, enc, exps, m1);
                rel_kernel<2, 2, ushort><<<g2, 256, 0, stream>>>(h1, atoms2, WiT2, bi2, WoT2, bo2, nullptr, nullptr, enc, exps, m2);
                rel_kernel<3, 2, ushort><<<g3, 256, 0, stream>>>(h1, atoms3, WiT3, bi3, WoT3, bo3, nullptr, nullptr, enc, exps, m3);
            }
            finalize_mm_kernel<<<(int)((NH + 255) / 256), 256, 0, stream>>>(enc, exps, mm);
        }

        if (layer == 0)
            update_kernel<float><<<N_NODES / 64, 256, 0, stream>>>(h0, mm, uWiT, ubi, uWoT, ubo, h1);
        else
            update_kernel<ushort><<<N_NODES / 64, 256, 0, stream>>>(h1, mm, uWiT, ubi, uWoT, ubo, h1);
    }

    readout_sum_kernel<<<NSTATES, 256, 0, stream>>>(h1, tsizes, agg);
    readout_mlp_kernel<<<NSTATES, 64, 0, stream>>>(agg, vWi, vbi, vWo, vbo,
                                                   dWi, dbi, dWo, dbo, out);
}

// Round 4
// 953.274 us; speedup vs baseline: 10.9269x; 2.1852x over previous
//
#include <hip/hip_runtime.h>
#include <math.h>

#define N_NODES 131072
#define NSTATES 64
#define NH ((size_t)N_NODES * 64)

typedef short bf16x8 __attribute__((ext_vector_type(8)));
typedef float f32x4 __attribute__((ext_vector_type(4)));

__device__ __forceinline__ ushort f2bf(float f) {
    unsigned u = __float_as_uint(f);
    return (ushort)((u + 0x7fffu + ((u >> 16) & 1u)) >> 16);
}
__device__ __forceinline__ float bf2f(ushort h) {
    return __uint_as_float(((unsigned)h) << 16);
}
// mish(x) = x*tanh(softplus(x)) = x*(t^2+2t)/(t^2+2t+2), t=e^x
__device__ __forceinline__ float mishf(float x) {
    if (x > 30.f) return x;
    float t = __builtin_amdgcn_exp2f(1.4426950408889634f * x);
    float r = t * t + 2.f * t;
    return x * r * __builtin_amdgcn_rcpf(r + 2.f);
}
// order-preserving f32 -> u32 (0 only for -NaN => "empty" sentinel)
__device__ __forceinline__ unsigned enc_f(float f) {
    unsigned u = __float_as_uint(f);
    return (u & 0x80000000u) ? ~u : (u | 0x80000000u);
}
__device__ __forceinline__ float dec_f(unsigned k) {
    unsigned u = (k & 0x80000000u) ? (k & 0x7fffffffu) : ~k;
    return __uint_as_float(u);
}

__device__ __forceinline__ bf16x8 load8f(const float* p) {
    const float4* q = (const float4*)p;
    float4 v0 = q[0], v1 = q[1];
    bf16x8 u;
    u[0] = (short)f2bf(v0.x); u[1] = (short)f2bf(v0.y);
    u[2] = (short)f2bf(v0.z); u[3] = (short)f2bf(v0.w);
    u[4] = (short)f2bf(v1.x); u[5] = (short)f2bf(v1.y);
    u[6] = (short)f2bf(v1.z); u[7] = (short)f2bf(v1.w);
    return u;
}

// ---------------------------------------------------------------------------
// h f32 -> bf16
// ---------------------------------------------------------------------------
__global__ __launch_bounds__(256) void h2bf_kernel(
    const float* __restrict__ h, ushort* __restrict__ hb)
{
    size_t i = ((size_t)blockIdx.x * 256 + threadIdx.x) * 8;
    if (i >= NH) return;
    *(bf16x8*)(hb + i) = load8f(h + i);
}

// ---------------------------------------------------------------------------
// weight convert: W [K(in)][Nc(out)] f32 -> WT [Nc][K] bf16 (transposed)
// ---------------------------------------------------------------------------
__global__ __launch_bounds__(256) void wt_conv_kernel(
    const float* __restrict__ W, ushort* __restrict__ WT, int K, int Nc)
{
    int i = blockIdx.x * 256 + threadIdx.x;
    if (i >= K * Nc) return;
    int o = i / K, k = i % K;
    WT[(size_t)o * K + k] = f2bf(W[(size_t)k * Nc + o]);
}

// ---------------------------------------------------------------------------
// CSR build
// ---------------------------------------------------------------------------
__global__ __launch_bounds__(256) void count_kernel(
    const int* __restrict__ atoms, int T, unsigned* __restrict__ cnt)
{
    int i = blockIdx.x * 256 + threadIdx.x;
    if (i < T) atomicAdd(&cnt[atoms[i]], 1u);
}

__global__ __launch_bounds__(256) void scan1_kernel(
    const unsigned* __restrict__ cnt, unsigned* __restrict__ base,
    unsigned* __restrict__ totals)
{
    __shared__ unsigned sm[256];
    int t = threadIdx.x, blk = blockIdx.x;
    int i0 = blk * 512;
    unsigned a = cnt[i0 + 2 * t], bb = cnt[i0 + 2 * t + 1];
    unsigned p = a + bb;
    sm[t] = p;
    __syncthreads();
    for (int off = 1; off < 256; off <<= 1) {
        unsigned v = (t >= off) ? sm[t - off] : 0u;
        __syncthreads();
        sm[t] += v;
        __syncthreads();
    }
    unsigned incl = sm[t];
    base[i0 + 2 * t]     = incl - p;
    base[i0 + 2 * t + 1] = incl - p + a;
    if (t == 255) totals[blk] = sm[255];
}

__global__ __launch_bounds__(256) void scan2_kernel(
    unsigned* __restrict__ base, const unsigned* __restrict__ totals)
{
    __shared__ unsigned ps[4];
    int t = threadIdx.x, blk = blockIdx.x;
    int lane = t & 63, wv = t >> 6;
    unsigned v = (t < blk) ? totals[t] : 0u;
    #pragma unroll
    for (int o = 32; o >= 1; o >>= 1) v += (unsigned)__shfl_xor((int)v, o);
    if (lane == 0) ps[wv] = v;
    __syncthreads();
    unsigned off = ps[0] + ps[1] + ps[2] + ps[3];
    int i0 = blk * 512;
    base[i0 + 2 * t]     += off;
    base[i0 + 2 * t + 1] += off;
}

__global__ __launch_bounds__(256) void copy_pos_kernel(
    const unsigned* __restrict__ base, unsigned* __restrict__ pos)
{
    int i = blockIdx.x * 256 + threadIdx.x;
    if (i < N_NODES) pos[i] = base[i];
}

// ---------------------------------------------------------------------------
// Relation MLP (bf16 MFMA, column-split waves):
//   y = x + mish(x@Wi+bi)@Wo+bo
// MODE 0: scatter rows to CSR slots (parallel slot atomics)
// MODE 1: atomicMax enc        (fallback pass 1)
// MODE 2: atomicAdd exp-sum    (fallback pass 2)
// ---------------------------------------------------------------------------
template<int ARITY, int MODE>
__global__ __launch_bounds__(256, (ARITY == 3) ? 3 : 4)
void rel_kernel(const ushort* __restrict__ h, const int* __restrict__ atoms,
                const ushort* __restrict__ WiT, const float* __restrict__ bi,
                const ushort* __restrict__ WoT, const float* __restrict__ bo,
                unsigned* __restrict__ pos, ushort* __restrict__ y_sorted,
                unsigned* __restrict__ enc, float* __restrict__ exps, int m)
{
    constexpr int AE  = ARITY * 64;
    constexpr int BM  = 64;
    constexpr int NTW = AE / 64;            // 16-col frags per wave
    constexpr int KS  = AE / 32;            // K steps
    constexpr int S   = AE * 2;             // LDS row stride bytes
    __shared__ __align__(16) ushort xs[BM * AE];
    __shared__ __align__(16) ushort ts[BM * AE];
    __shared__ unsigned slot_sm[BM * ARITY];
    const int tid = threadIdx.x, lane = tid & 63, wv = tid >> 6;
    const int a0 = blockIdx.x * BM;

    // ---- stage gathered x rows (bf16, XOR-swizzled) ----
    for (int task = tid; task < BM * (AE / 8); task += 256) {
        int r  = task / (AE / 8);
        int c8 = task % (AE / 8);
        int atom = a0 + r;
        bf16x8 u = {0, 0, 0, 0, 0, 0, 0, 0};
        if (atom < m) {
            int node = atoms[atom * ARITY + (c8 >> 3)];
            u = *(const bf16x8*)(h + (size_t)node * 64 + (size_t)(c8 & 7) * 8);
        }
        *(bf16x8*)((char*)xs + r * S + ((c8 * 16) ^ ((r & 7) << 4))) = u;
    }
    __syncthreads();

    const int cw0 = wv * NTW * 16;          // wave's first output column
    const int kg  = (lane >> 4) * 8;
    const int cl  = lane & 15;

    // ---- matmul1: inner = x @ Wi + bi ----
    f32x4 acc[4][NTW];
    #pragma unroll
    for (int n = 0; n < NTW; n++) {
        float b = bi[cw0 + n * 16 + cl];
        #pragma unroll
        for (int a = 0; a < 4; a++) acc[a][n] = (f32x4){b, b, b, b};
    }
    #pragma unroll
    for (int ks = 0; ks < KS; ks++) {
        bf16x8 bf[NTW];
        #pragma unroll
        for (int n = 0; n < NTW; n++)
            bf[n] = *(const bf16x8*)(WiT + (size_t)(cw0 + n * 16 + cl) * AE + ks * 32 + kg);
        #pragma unroll
        for (int a = 0; a < 4; a++) {
            int row = a * 16 + cl;
            bf16x8 af = *(const bf16x8*)((char*)xs + row * S + (((ks * 32 + kg) * 2) ^ ((row & 7) << 4)));
            #pragma unroll
            for (int n = 0; n < NTW; n++)
                acc[a][n] = __builtin_amdgcn_mfma_f32_16x16x32_bf16(af, bf[n], acc[a][n], 0, 0, 0);
        }
    }
    // D layout: row=(lane>>4)*4+j, col=lane&15  (m89-verified)
    #pragma unroll
    for (int a = 0; a < 4; a++)
        #pragma unroll
        for (int n = 0; n < NTW; n++)
            #pragma unroll
            for (int j = 0; j < 4; j++) {
                int row = a * 16 + (lane >> 4) * 4 + j;
                int col = cw0 + n * 16 + cl;
                *(ushort*)((char*)ts + row * S + ((col * 2) ^ ((row & 7) << 4))) = f2bf(mishf(acc[a][n][j]));
            }
    __syncthreads();

    // ---- matmul2: out = t @ Wo + bo ----
    #pragma unroll
    for (int n = 0; n < NTW; n++) {
        float b = bo[cw0 + n * 16 + cl];
        #pragma unroll
        for (int a = 0; a < 4; a++) acc[a][n] = (f32x4){b, b, b, b};
    }
    #pragma unroll
    for (int ks = 0; ks < KS; ks++) {
        bf16x8 bf[NTW];
        #pragma unroll
        for (int n = 0; n < NTW; n++)
            bf[n] = *(const bf16x8*)(WoT + (size_t)(cw0 + n * 16 + cl) * AE + ks * 32 + kg);
        #pragma unroll
        for (int a = 0; a < 4; a++) {
            int row = a * 16 + cl;
            bf16x8 af = *(const bf16x8*)((char*)ts + row * S + (((ks * 32 + kg) * 2) ^ ((row & 7) << 4)));
            #pragma unroll
            for (int n = 0; n < NTW; n++)
                acc[a][n] = __builtin_amdgcn_mfma_f32_16x16x32_bf16(af, bf[n], acc[a][n], 0, 0, 0);
        }
    }
    // residual y = x + out -> back into xs (bf16)
    #pragma unroll
    for (int a = 0; a < 4; a++)
        #pragma unroll
        for (int n = 0; n < NTW; n++)
            #pragma unroll
            for (int j = 0; j < 4; j++) {
                int row = a * 16 + (lane >> 4) * 4 + j;
                int col = cw0 + n * 16 + cl;
                ushort* xp = (ushort*)((char*)xs + row * S + ((col * 2) ^ ((row & 7) << 4)));
                *xp = f2bf(bf2f(*xp) + acc[a][n][j]);
            }
    __syncthreads();

    // ---- epilogue ----
    const int nrows = BM * ARITY;
    if (MODE == 0) {
        // parallel slot acquisition: one thread per message row
        if (tid < nrows) {
            int grow = a0 * ARITY + tid;
            unsigned s = 0u;
            if (grow < m * ARITY) s = atomicAdd(&pos[atoms[grow]], 1u);
            slot_sm[tid] = s;
        }
        __syncthreads();
        for (int rr = wv; rr < nrows; rr += 4) {
            int grow = a0 * ARITY + rr;
            if (grow >= m * ARITY) break;
            int r = rr / ARITY, c = (rr % ARITY) * 64 + lane;
            ushort yu = *(ushort*)((char*)xs + r * S + ((c * 2) ^ ((r & 7) << 4)));
            y_sorted[(size_t)slot_sm[rr] * 64 + lane] = yu;
        }
    } else {
        for (int rr = wv; rr < nrows; rr += 4) {
            int grow = a0 * ARITY + rr;
            if (grow >= m * ARITY) break;
            int node = atoms[grow];
            int r = rr / ARITY, c = (rr % ARITY) * 64 + lane;
            ushort yu = *(ushort*)((char*)xs + r * S + ((c * 2) ^ ((r & 7) << 4)));
            if (MODE == 1) {
                atomicMax(&enc[(size_t)node * 64 + lane], enc_f(bf2f(yu)));
            } else {
                size_t cell = (size_t)node * 64 + lane;
                float mx = dec_f(enc[cell]);
                atomicAdd(&exps[cell], __builtin_amdgcn_exp2f(17.312340490667562f * (bf2f(yu) - mx)));
            }
        }
    }
}

// ---------------------------------------------------------------------------
// Per-node smooth-max over CSR-sorted messages (no atomics)
// ---------------------------------------------------------------------------
__global__ __launch_bounds__(256) void aggregate_kernel(
    const ushort* __restrict__ y_sorted, const unsigned* __restrict__ base,
    const unsigned* __restrict__ cnt, ushort* __restrict__ mm)
{
    int node = blockIdx.x * 4 + (threadIdx.x >> 6);
    int lane = threadIdx.x & 63;
    unsigned b = base[node], c = cnt[node];
    const ushort* p = y_sorted + (size_t)b * 64 + lane;
    float mx = -3.402823466e38f;
    for (unsigned j = 0; j < c; j++)
        mx = fmaxf(mx, bf2f(p[(size_t)j * 64]));
    float me = c ? mx : 0.f;
    float s = 0.f;
    for (unsigned j = 0; j < c; j++)
        s += __builtin_amdgcn_exp2f(17.312340490667562f * (bf2f(p[(size_t)j * 64]) - me));
    float r = __builtin_amdgcn_logf(1e-16f + s) * 0.05776226504666211f + me;
    mm[(size_t)node * 64 + lane] = f2bf(r);
}

// fallback finalize: mm from (enc, exps)
__global__ __launch_bounds__(256) void finalize_mm_kernel(
    const unsigned* __restrict__ enc, const float* __restrict__ exps,
    ushort* __restrict__ mm)
{
    size_t i = (size_t)blockIdx.x * 256 + threadIdx.x;
    if (i >= NH) return;
    unsigned key = enc[i];
    float mx = key ? dec_f(key) : 0.f;
    float r = __builtin_amdgcn_logf(1e-16f + exps[i]) * 0.05776226504666211f + mx;
    mm[i] = f2bf(r);
}

// ---------------------------------------------------------------------------
// Node update (bf16 MFMA, in-place): h = h + mish([mm,h]@uWi+ubi)@uWo+ubo
// ---------------------------------------------------------------------------
__global__ __launch_bounds__(256, 4)
void update_kernel(ushort* __restrict__ hio, const ushort* __restrict__ mm,
                   const ushort* __restrict__ uWiT, const float* __restrict__ ubi,
                   const ushort* __restrict__ uWoT, const float* __restrict__ ubo)
{
    constexpr int AE = 128, BM = 64, S = 256, NTW = 2, KS = 4;
    __shared__ __align__(16) ushort xs[BM * AE];
    __shared__ __align__(16) ushort ts[BM * AE];
    const int tid = threadIdx.x, lane = tid & 63, wv = tid >> 6;
    const int n0 = blockIdx.x * BM;

    for (int task = tid; task < BM * 16; task += 256) {
        int r = task >> 4, c8 = task & 15;
        int node = n0 + r;
        bf16x8 u;
        if (c8 < 8) u = *(const bf16x8*)(mm  + (size_t)node * 64 + c8 * 8);
        else        u = *(const bf16x8*)(hio + (size_t)node * 64 + (size_t)(c8 - 8) * 8);
        *(bf16x8*)((char*)xs + r * S + ((c8 * 16) ^ ((r & 7) << 4))) = u;
    }
    __syncthreads();

    const int cw0 = wv * NTW * 16;
    const int kg  = (lane >> 4) * 8;
    const int cl  = lane & 15;

    f32x4 acc[4][NTW];
    #pragma unroll
    for (int n = 0; n < NTW; n++) {
        float b = ubi[cw0 + n * 16 + cl];
        #pragma unroll
        for (int a = 0; a < 4; a++) acc[a][n] = (f32x4){b, b, b, b};
    }
    #pragma unroll
    for (int ks = 0; ks < KS; ks++) {
        bf16x8 bf[NTW];
        #pragma unroll
        for (int n = 0; n < NTW; n++)
            bf[n] = *(const bf16x8*)(uWiT + (size_t)(cw0 + n * 16 + cl) * AE + ks * 32 + kg);
        #pragma unroll
        for (int a = 0; a < 4; a++) {
            int row = a * 16 + cl;
            bf16x8 af = *(const bf16x8*)((char*)xs + row * S + (((ks * 32 + kg) * 2) ^ ((row & 7) << 4)));
            #pragma unroll
            for (int n = 0; n < NTW; n++)
                acc[a][n] = __builtin_amdgcn_mfma_f32_16x16x32_bf16(af, bf[n], acc[a][n], 0, 0, 0);
        }
    }
    #pragma unroll
    for (int a = 0; a < 4; a++)
        #pragma unroll
        for (int n = 0; n < NTW; n++)
            #pragma unroll
            for (int j = 0; j < 4; j++) {
                int row = a * 16 + (lane >> 4) * 4 + j;
                int col = cw0 + n * 16 + cl;
                *(ushort*)((char*)ts + row * S + ((col * 2) ^ ((row & 7) << 4))) = f2bf(mishf(acc[a][n][j]));
            }
    __syncthreads();

    // matmul2: 64 output cols -> 1 col-frag per wave
    f32x4 acc2[4];
    {
        float b = ubo[wv * 16 + cl];
        #pragma unroll
        for (int a = 0; a < 4; a++) acc2[a] = (f32x4){b, b, b, b};
    }
    #pragma unroll
    for (int ks = 0; ks < KS; ks++) {
        bf16x8 bf = *(const bf16x8*)(uWoT + (size_t)(wv * 16 + cl) * AE + ks * 32 + kg);
        #pragma unroll
        for (int a = 0; a < 4; a++) {
            int row = a * 16 + cl;
            bf16x8 af = *(const bf16x8*)((char*)ts + row * S + (((ks * 32 + kg) * 2) ^ ((row & 7) << 4)));
            acc2[a] = __builtin_amdgcn_mfma_f32_16x16x32_bf16(af, bf, acc2[a], 0, 0, 0);
        }
    }
    #pragma unroll
    for (int a = 0; a < 4; a++)
        #pragma unroll
        for (int j = 0; j < 4; j++) {
            int row = a * 16 + (lane >> 4) * 4 + j;
            int col = wv * 16 + cl;
            // residual from LDS copy of h (cols 64..127)
            int hc = 64 + col;
            float hold = bf2f(*(ushort*)((char*)xs + row * S + ((hc * 2) ^ ((row & 7) << 4))));
            hio[(size_t)(n0 + row) * 64 + col] = f2bf(hold + acc2[a][j]);
        }
}

// ---------------------------------------------------------------------------
// Readout
// ---------------------------------------------------------------------------
__global__ __launch_bounds__(256) void readout_sum_kernel(
    const ushort* __restrict__ h, const int* __restrict__ toksz,
    float* __restrict__ agg)
{
    int s = blockIdx.x;
    int off = 0;
    for (int i = 0; i < s; i++) off += toksz[i];
    int cntr = toksz[s];
    int col = threadIdx.x & 63, rg = threadIdx.x >> 6;
    float acc = 0.f;
    for (int r = rg; r < cntr; r += 4)
        acc += bf2f(h[(size_t)(off + r) * 64 + col]);
    __shared__ float red[4][64];
    red[rg][col] = acc;
    __syncthreads();
    if (rg == 0)
        agg[s * 64 + col] = red[0][col] + red[1][col] + red[2][col] + red[3][col];
}

__global__ __launch_bounds__(64) void readout_mlp_kernel(
    const float* __restrict__ agg,
    const float* __restrict__ vWi, const float* __restrict__ vbi,
    const float* __restrict__ vWo, const float* __restrict__ vbo,
    const float* __restrict__ dWi, const float* __restrict__ dbi,
    const float* __restrict__ dWo, const float* __restrict__ dbo,
    float* __restrict__ out)
{
    int s = blockIdx.x;
    int lane = threadIdx.x;
    float accv = vbi[lane], accd = dbi[lane];
    for (int k = 0; k < 64; k++) {
        float a = agg[s * 64 + k];
        accv = fmaf(a, vWi[k * 64 + lane], accv);
        accd = fmaf(a, dWi[k * 64 + lane], accd);
    }
    float pv = mishf(accv) * vWo[lane];
    float pd = mishf(accd) * dWo[lane];
    #pragma unroll
    for (int o = 1; o < 64; o <<= 1) {
        pv += __shfl_xor(pv, o);
        pd += __shfl_xor(pd, o);
    }
    if (lane == 0) { out[s] = pv + vbo[0]; out[64 + s] = pd + dbo[0]; }
}

// ---------------------------------------------------------------------------
extern "C" void kernel_launch(void* const* d_in, const int* in_sizes, int n_in,
                              void* d_out, int out_size, void* d_ws, size_t ws_size,
                              hipStream_t stream)
{
    const float* h0   = (const float*)d_in[0];
    const int* atoms1 = (const int*)d_in[1];
    const int* atoms2 = (const int*)d_in[2];
    const int* atoms3 = (const int*)d_in[3];
    const int* tsizes = (const int*)d_in[4];
    const float* Wi1 = (const float*)d_in[5],  *bi1 = (const float*)d_in[6];
    const float* Wo1 = (const float*)d_in[7],  *bo1 = (const float*)d_in[8];
    const float* Wi2 = (const float*)d_in[9],  *bi2 = (const float*)d_in[10];
    const float* Wo2 = (const float*)d_in[11], *bo2 = (const float*)d_in[12];
    const float* Wi3 = (const float*)d_in[13], *bi3 = (const float*)d_in[14];
    const float* Wo3 = (const float*)d_in[15], *bo3 = (const float*)d_in[16];
    const float* uWi = (const float*)d_in[17], *ubi = (const float*)d_in[18];
    const float* uWo = (const float*)d_in[19], *ubo = (const float*)d_in[20];
    const float* vWi = (const float*)d_in[21], *vbi = (const float*)d_in[22];
    const float* vWo = (const float*)d_in[23], *vbo = (const float*)d_in[24];
    const float* dWi = (const float*)d_in[25], *dbi = (const float*)d_in[26];
    const float* dWo = (const float*)d_in[27], *dbo = (const float*)d_in[28];
    float* out = (float*)d_out;

    const int rows1 = in_sizes[1];
    const int rows2 = in_sizes[2];
    const int rows3 = in_sizes[3];
    const int m1 = rows1, m2 = rows2 / 2, m3 = rows3 / 3;
    const int T = rows1 + rows2 + rows3;

    char* w = (char*)d_ws;
    auto alloc = [&](size_t bytes) { char* p = w; w += (bytes + 255) & ~(size_t)255; return p; };
    ushort* h1       = (ushort*)alloc(NH * 2);
    ushort* mm       = (ushort*)alloc(NH * 2);
    unsigned* cnt    = (unsigned*)alloc(N_NODES * 4);
    unsigned* base   = (unsigned*)alloc(N_NODES * 4);
    unsigned* pos    = (unsigned*)alloc(N_NODES * 4);
    unsigned* totals = (unsigned*)alloc(256 * 4);
    float* agg       = (float*)alloc(NSTATES * 64 * 4);
    ushort* WiT1 = (ushort*)alloc(64 * 64 * 2);
    ushort* WoT1 = (ushort*)alloc(64 * 64 * 2);
    ushort* WiT2 = (ushort*)alloc(128 * 128 * 2);
    ushort* WoT2 = (ushort*)alloc(128 * 128 * 2);
    ushort* WiT3 = (ushort*)alloc(192 * 192 * 2);
    ushort* WoT3 = (ushort*)alloc(192 * 192 * 2);
    ushort* uWiT = (ushort*)alloc(128 * 128 * 2);
    ushort* uWoT = (ushort*)alloc(64 * 128 * 2);
    char* tail = w;

    size_t y_bytes  = (size_t)T * 64 * 2;
    const bool csr  = ((size_t)(tail - (char*)d_ws) + ((y_bytes + 255) & ~(size_t)255)) <= ws_size;
    ushort* y_sorted = nullptr;
    unsigned* enc = nullptr;
    float* exps = nullptr;
    if (csr) {
        y_sorted = (ushort*)alloc(y_bytes);
    } else {
        enc  = (unsigned*)alloc(NH * 4);
        exps = (float*)alloc(NH * 4);
    }

    h2bf_kernel<<<(int)(NH / 8 / 256), 256, 0, stream>>>(h0, h1);

    wt_conv_kernel<<<(64 * 64 + 255) / 256, 256, 0, stream>>>(Wi1, WiT1, 64, 64);
    wt_conv_kernel<<<(64 * 64 + 255) / 256, 256, 0, stream>>>(Wo1, WoT1, 64, 64);
    wt_conv_kernel<<<(128 * 128 + 255) / 256, 256, 0, stream>>>(Wi2, WiT2, 128, 128);
    wt_conv_kernel<<<(128 * 128 + 255) / 256, 256, 0, stream>>>(Wo2, WoT2, 128, 128);
    wt_conv_kernel<<<(192 * 192 + 255) / 256, 256, 0, stream>>>(Wi3, WiT3, 192, 192);
    wt_conv_kernel<<<(192 * 192 + 255) / 256, 256, 0, stream>>>(Wo3, WoT3, 192, 192);
    wt_conv_kernel<<<(128 * 128 + 255) / 256, 256, 0, stream>>>(uWi, uWiT, 128, 128);
    wt_conv_kernel<<<(128 * 64 + 255) / 256, 256, 0, stream>>>(uWo, uWoT, 128, 64);

    if (csr) {
        hipMemsetAsync(cnt, 0, N_NODES * 4, stream);
        count_kernel<<<(rows1 + 255) / 256, 256, 0, stream>>>(atoms1, rows1, cnt);
        count_kernel<<<(rows2 + 255) / 256, 256, 0, stream>>>(atoms2, rows2, cnt);
        count_kernel<<<(rows3 + 255) / 256, 256, 0, stream>>>(atoms3, rows3, cnt);
        scan1_kernel<<<256, 256, 0, stream>>>(cnt, base, totals);
        scan2_kernel<<<256, 256, 0, stream>>>(base, totals);
    }

    const int g1 = (m1 + 63) / 64, g2 = (m2 + 63) / 64, g3 = (m3 + 63) / 64;

    for (int layer = 0; layer < 2; layer++) {
        if (csr) {
            copy_pos_kernel<<<(N_NODES + 255) / 256, 256, 0, stream>>>(base, pos);
            rel_kernel<1, 0><<<g1, 256, 0, stream>>>(h1, atoms1, WiT1, bi1, WoT1, bo1, pos, y_sorted, nullptr, nullptr, m1);
            rel_kernel<2, 0><<<g2, 256, 0, stream>>>(h1, atoms2, WiT2, bi2, WoT2, bo2, pos, y_sorted, nullptr, nullptr, m2);
            rel_kernel<3, 0><<<g3, 256, 0, stream>>>(h1, atoms3, WiT3, bi3, WoT3, bo3, pos, y_sorted, nullptr, nullptr, m3);
            aggregate_kernel<<<N_NODES / 4, 256, 0, stream>>>(y_sorted, base, cnt, mm);
        } else {
            hipMemsetAsync(enc, 0, NH * 8, stream);   // enc + exps
            rel_kernel<1, 1><<<g1, 256, 0, stream>>>(h1, atoms1, WiT1, bi1, WoT1, bo1, nullptr, nullptr, enc, exps, m1);
            rel_kernel<2, 1><<<g2, 256, 0, stream>>>(h1, atoms2, WiT2, bi2, WoT2, bo2, nullptr, nullptr, enc, exps, m2);
            rel_kernel<3, 1><<<g3, 256, 0, stream>>>(h1, atoms3, WiT3, bi3, WoT3, bo3, nullptr, nullptr, enc, exps, m3);
            rel_kernel<1, 2><<<g1, 256, 0, stream>>>(h1, atoms1, WiT1, bi1, WoT1, bo1, nullptr, nullptr, enc, exps, m1);
            rel_kernel<2, 2><<<g2, 256, 0, stream>>>(h1, atoms2, WiT2, bi2, WoT2, bo2, nullptr, nullptr, enc, exps, m2);
            rel_kernel<3, 2><<<g3, 256, 0, stream>>>(h1, atoms3, WiT3, bi3, WoT3, bo3, nullptr, nullptr, enc, exps, m3);
            finalize_mm_kernel<<<(int)((NH + 255) / 256), 256, 0, stream>>>(enc, exps, mm);
        }
        update_kernel<<<N_NODES / 64, 256, 0, stream>>>(h1, mm, uWiT, ubi, uWoT, ubo);
    }

    readout_sum_kernel<<<NSTATES, 256, 0, stream>>>(h1, tsizes, agg);
    readout_mlp_kernel<<<NSTATES, 64, 0, stream>>>(agg, vWi, vbi, vWo, vbo,
                                                   dWi, dbi, dWo, dbo, out);
}

// Round 5
// 829.479 us; speedup vs baseline: 12.5577x; 1.1492x over previous
//
#include <hip/hip_runtime.h>
#include <math.h>

#define N_NODES 131072
#define NSTATES 64
#define NH ((size_t)N_NODES * 64)

typedef short bf16x8 __attribute__((ext_vector_type(8)));
typedef float f32x4 __attribute__((ext_vector_type(4)));

__device__ __forceinline__ ushort f2bf(float f) {
    unsigned u = __float_as_uint(f);
    return (ushort)((u + 0x7fffu + ((u >> 16) & 1u)) >> 16);
}
__device__ __forceinline__ float bf2f(ushort h) {
    return __uint_as_float(((unsigned)h) << 16);
}
// mish(x) = x*tanh(softplus(x)) = x*(t^2+2t)/(t^2+2t+2), t=e^x
__device__ __forceinline__ float mishf(float x) {
    if (x > 30.f) return x;
    float t = __builtin_amdgcn_exp2f(1.4426950408889634f * x);
    float r = t * t + 2.f * t;
    return x * r * __builtin_amdgcn_rcpf(r + 2.f);
}
// order-preserving f32 -> u32 (0 only for -NaN => "empty" sentinel)
__device__ __forceinline__ unsigned enc_f(float f) {
    unsigned u = __float_as_uint(f);
    return (u & 0x80000000u) ? ~u : (u | 0x80000000u);
}
__device__ __forceinline__ float dec_f(unsigned k) {
    unsigned u = (k & 0x80000000u) ? (k & 0x7fffffffu) : ~k;
    return __uint_as_float(u);
}

__device__ __forceinline__ bf16x8 load8f(const float* p) {
    const float4* q = (const float4*)p;
    float4 v0 = q[0], v1 = q[1];
    bf16x8 u;
    u[0] = (short)f2bf(v0.x); u[1] = (short)f2bf(v0.y);
    u[2] = (short)f2bf(v0.z); u[3] = (short)f2bf(v0.w);
    u[4] = (short)f2bf(v1.x); u[5] = (short)f2bf(v1.y);
    u[6] = (short)f2bf(v1.z); u[7] = (short)f2bf(v1.w);
    return u;
}

// ---------------------------------------------------------------------------
// h f32 -> bf16
// ---------------------------------------------------------------------------
__global__ __launch_bounds__(256) void h2bf_kernel(
    const float* __restrict__ h, ushort* __restrict__ hb)
{
    size_t i = ((size_t)blockIdx.x * 256 + threadIdx.x) * 8;
    if (i >= NH) return;
    *(bf16x8*)(hb + i) = load8f(h + i);
}

// ---------------------------------------------------------------------------
// fused weight convert: 8 jobs, W [K][Nc] f32 -> WT [Nc][K] bf16
// ---------------------------------------------------------------------------
struct WtJob  { const float* src; ushort* dst; int K; int Nc; int start; };
struct WtJobs { WtJob j[8]; int total; };

__global__ __launch_bounds__(256) void wt_conv_all_kernel(WtJobs jobs)
{
    int i = blockIdx.x * 256 + threadIdx.x;
    if (i >= jobs.total) return;
    int jj = 0;
    #pragma unroll
    for (int k = 1; k < 8; k++) if (i >= jobs.j[k].start) jj = k;
    WtJob jb = jobs.j[jj];
    int local = i - jb.start;
    int o = local / jb.K, k = local % jb.K;
    jb.dst[(size_t)o * jb.K + k] = f2bf(jb.src[(size_t)k * jb.Nc + o]);
}

// ---------------------------------------------------------------------------
// CSR build
// ---------------------------------------------------------------------------
__global__ __launch_bounds__(256) void count_kernel(
    const int* __restrict__ atoms, int T, unsigned* __restrict__ cnt)
{
    int i = blockIdx.x * 256 + threadIdx.x;
    if (i < T) atomicAdd(&cnt[atoms[i]], 1u);
}

__global__ __launch_bounds__(256) void scan1_kernel(
    const unsigned* __restrict__ cnt, unsigned* __restrict__ base,
    unsigned* __restrict__ totals)
{
    __shared__ unsigned sm[256];
    int t = threadIdx.x, blk = blockIdx.x;
    int i0 = blk * 512;
    unsigned a = cnt[i0 + 2 * t], bb = cnt[i0 + 2 * t + 1];
    unsigned p = a + bb;
    sm[t] = p;
    __syncthreads();
    for (int off = 1; off < 256; off <<= 1) {
        unsigned v = (t >= off) ? sm[t - off] : 0u;
        __syncthreads();
        sm[t] += v;
        __syncthreads();
    }
    unsigned incl = sm[t];
    base[i0 + 2 * t]     = incl - p;
    base[i0 + 2 * t + 1] = incl - p + a;
    if (t == 255) totals[blk] = sm[255];
}

// also seeds pos = base (replaces copy_pos for layer 0)
__global__ __launch_bounds__(256) void scan2_kernel(
    unsigned* __restrict__ base, unsigned* __restrict__ pos,
    const unsigned* __restrict__ totals)
{
    __shared__ unsigned ps[4];
    int t = threadIdx.x, blk = blockIdx.x;
    int lane = t & 63, wv = t >> 6;
    unsigned v = (t < blk) ? totals[t] : 0u;
    #pragma unroll
    for (int o = 32; o >= 1; o >>= 1) v += (unsigned)__shfl_xor((int)v, o);
    if (lane == 0) ps[wv] = v;
    __syncthreads();
    unsigned off = ps[0] + ps[1] + ps[2] + ps[3];
    int i0 = blk * 512;
    unsigned b0 = base[i0 + 2 * t] + off;
    unsigned b1 = base[i0 + 2 * t + 1] + off;
    base[i0 + 2 * t]     = b0;  pos[i0 + 2 * t]     = b0;
    base[i0 + 2 * t + 1] = b1;  pos[i0 + 2 * t + 1] = b1;
}

// ---------------------------------------------------------------------------
// Relation MLP (bf16 MFMA, column-split waves):
//   y = x + mish(x@Wi+bi)@Wo+bo
// MODE 0: scatter rows to CSR slots (parallel slot atomics)
// MODE 1: atomicMax enc        (fallback pass 1)
// MODE 2: atomicAdd exp-sum    (fallback pass 2)
// ---------------------------------------------------------------------------
template<int ARITY, int MODE>
__global__ __launch_bounds__(256, (ARITY == 3) ? 3 : 4)
void rel_kernel(const ushort* __restrict__ h, const int* __restrict__ atoms,
                const ushort* __restrict__ WiT, const float* __restrict__ bi,
                const ushort* __restrict__ WoT, const float* __restrict__ bo,
                unsigned* __restrict__ pos, ushort* __restrict__ y_sorted,
                unsigned* __restrict__ enc, float* __restrict__ exps, int m)
{
    constexpr int AE  = ARITY * 64;
    constexpr int BM  = 64;
    constexpr int NTW = AE / 64;            // 16-col frags per wave
    constexpr int KS  = AE / 32;            // K steps
    constexpr int S   = AE * 2;             // LDS row stride bytes
    __shared__ __align__(16) ushort xs[BM * AE];
    __shared__ __align__(16) ushort ts[BM * AE];
    __shared__ unsigned slot_sm[BM * ARITY];
    const int tid = threadIdx.x, lane = tid & 63, wv = tid >> 6;
    const int a0 = blockIdx.x * BM;

    // ---- stage gathered x rows (bf16, XOR-swizzled) ----
    for (int task = tid; task < BM * (AE / 8); task += 256) {
        int r  = task / (AE / 8);
        int c8 = task % (AE / 8);
        int atom = a0 + r;
        bf16x8 u = {0, 0, 0, 0, 0, 0, 0, 0};
        if (atom < m) {
            int node = atoms[atom * ARITY + (c8 >> 3)];
            u = *(const bf16x8*)(h + (size_t)node * 64 + (size_t)(c8 & 7) * 8);
        }
        *(bf16x8*)((char*)xs + r * S + ((c8 * 16) ^ ((r & 7) << 4))) = u;
    }
    __syncthreads();

    const int cw0 = wv * NTW * 16;          // wave's first output column
    const int kg  = (lane >> 4) * 8;
    const int cl  = lane & 15;

    // ---- matmul1: inner = x @ Wi + bi ----
    f32x4 acc[4][NTW];
    #pragma unroll
    for (int n = 0; n < NTW; n++) {
        float b = bi[cw0 + n * 16 + cl];
        #pragma unroll
        for (int a = 0; a < 4; a++) acc[a][n] = (f32x4){b, b, b, b};
    }
    #pragma unroll
    for (int ks = 0; ks < KS; ks++) {
        bf16x8 bf[NTW];
        #pragma unroll
        for (int n = 0; n < NTW; n++)
            bf[n] = *(const bf16x8*)(WiT + (size_t)(cw0 + n * 16 + cl) * AE + ks * 32 + kg);
        #pragma unroll
        for (int a = 0; a < 4; a++) {
            int row = a * 16 + cl;
            bf16x8 af = *(const bf16x8*)((char*)xs + row * S + (((ks * 32 + kg) * 2) ^ ((row & 7) << 4)));
            #pragma unroll
            for (int n = 0; n < NTW; n++)
                acc[a][n] = __builtin_amdgcn_mfma_f32_16x16x32_bf16(af, bf[n], acc[a][n], 0, 0, 0);
        }
    }
    // D layout: row=(lane>>4)*4+j, col=lane&15  (m89-verified)
    #pragma unroll
    for (int a = 0; a < 4; a++)
        #pragma unroll
        for (int n = 0; n < NTW; n++)
            #pragma unroll
            for (int j = 0; j < 4; j++) {
                int row = a * 16 + (lane >> 4) * 4 + j;
                int col = cw0 + n * 16 + cl;
                *(ushort*)((char*)ts + row * S + ((col * 2) ^ ((row & 7) << 4))) = f2bf(mishf(acc[a][n][j]));
            }
    __syncthreads();

    // ---- matmul2: out = t @ Wo + bo ----
    #pragma unroll
    for (int n = 0; n < NTW; n++) {
        float b = bo[cw0 + n * 16 + cl];
        #pragma unroll
        for (int a = 0; a < 4; a++) acc[a][n] = (f32x4){b, b, b, b};
    }
    #pragma unroll
    for (int ks = 0; ks < KS; ks++) {
        bf16x8 bf[NTW];
        #pragma unroll
        for (int n = 0; n < NTW; n++)
            bf[n] = *(const bf16x8*)(WoT + (size_t)(cw0 + n * 16 + cl) * AE + ks * 32 + kg);
        #pragma unroll
        for (int a = 0; a < 4; a++) {
            int row = a * 16 + cl;
            bf16x8 af = *(const bf16x8*)((char*)ts + row * S + (((ks * 32 + kg) * 2) ^ ((row & 7) << 4)));
            #pragma unroll
            for (int n = 0; n < NTW; n++)
                acc[a][n] = __builtin_amdgcn_mfma_f32_16x16x32_bf16(af, bf[n], acc[a][n], 0, 0, 0);
        }
    }
    // residual y = x + out -> back into xs (bf16)
    #pragma unroll
    for (int a = 0; a < 4; a++)
        #pragma unroll
        for (int n = 0; n < NTW; n++)
            #pragma unroll
            for (int j = 0; j < 4; j++) {
                int row = a * 16 + (lane >> 4) * 4 + j;
                int col = cw0 + n * 16 + cl;
                ushort* xp = (ushort*)((char*)xs + row * S + ((col * 2) ^ ((row & 7) << 4)));
                *xp = f2bf(bf2f(*xp) + acc[a][n][j]);
            }
    __syncthreads();

    // ---- epilogue ----
    const int nrows = BM * ARITY;
    if (MODE == 0) {
        // parallel slot acquisition: one thread per message row
        if (tid < nrows) {
            int grow = a0 * ARITY + tid;
            unsigned s = 0u;
            if (grow < m * ARITY) s = atomicAdd(&pos[atoms[grow]], 1u);
            slot_sm[tid] = s;
        }
        __syncthreads();
        for (int rr = wv; rr < nrows; rr += 4) {
            int grow = a0 * ARITY + rr;
            if (grow >= m * ARITY) break;
            int r = rr / ARITY, c = (rr % ARITY) * 64 + lane;
            ushort yu = *(ushort*)((char*)xs + r * S + ((c * 2) ^ ((r & 7) << 4)));
            y_sorted[(size_t)slot_sm[rr] * 64 + lane] = yu;
        }
    } else {
        for (int rr = wv; rr < nrows; rr += 4) {
            int grow = a0 * ARITY + rr;
            if (grow >= m * ARITY) break;
            int node = atoms[grow];
            int r = rr / ARITY, c = (rr % ARITY) * 64 + lane;
            ushort yu = *(ushort*)((char*)xs + r * S + ((c * 2) ^ ((r & 7) << 4)));
            if (MODE == 1) {
                atomicMax(&enc[(size_t)node * 64 + lane], enc_f(bf2f(yu)));
            } else {
                size_t cell = (size_t)node * 64 + lane;
                float mx = dec_f(enc[cell]);
                atomicAdd(&exps[cell], __builtin_amdgcn_exp2f(17.312340490667562f * (bf2f(yu) - mx)));
            }
        }
    }
}

// ---------------------------------------------------------------------------
// Per-node smooth-max over CSR-sorted messages (no atomics).
// Side effect: pos[node] = base[node] (re-seeds pos for the next layer).
// ---------------------------------------------------------------------------
__global__ __launch_bounds__(256) void aggregate_kernel(
    const ushort* __restrict__ y_sorted, const unsigned* __restrict__ base,
    const unsigned* __restrict__ cnt, unsigned* __restrict__ pos,
    ushort* __restrict__ mm)
{
    int node = blockIdx.x * 4 + (threadIdx.x >> 6);
    int lane = threadIdx.x & 63;
    unsigned b = base[node], c = cnt[node];
    if (lane == 0) pos[node] = b;
    const ushort* p = y_sorted + (size_t)b * 64 + lane;
    float mx = -3.402823466e38f;
    for (unsigned j = 0; j < c; j++)
        mx = fmaxf(mx, bf2f(p[(size_t)j * 64]));
    float me = c ? mx : 0.f;
    float s = 0.f;
    for (unsigned j = 0; j < c; j++)
        s += __builtin_amdgcn_exp2f(17.312340490667562f * (bf2f(p[(size_t)j * 64]) - me));
    float r = __builtin_amdgcn_logf(1e-16f + s) * 0.05776226504666211f + me;
    mm[(size_t)node * 64 + lane] = f2bf(r);
}

// fallback finalize: mm from (enc, exps)
__global__ __launch_bounds__(256) void finalize_mm_kernel(
    const unsigned* __restrict__ enc, const float* __restrict__ exps,
    ushort* __restrict__ mm)
{
    size_t i = (size_t)blockIdx.x * 256 + threadIdx.x;
    if (i >= NH) return;
    unsigned key = enc[i];
    float mx = key ? dec_f(key) : 0.f;
    float r = __builtin_amdgcn_logf(1e-16f + exps[i]) * 0.05776226504666211f + mx;
    mm[i] = f2bf(r);
}

// ---------------------------------------------------------------------------
// Node update (bf16 MFMA, in-place): h = h + mish([mm,h]@uWi+ubi)@uWo+ubo
// ---------------------------------------------------------------------------
__global__ __launch_bounds__(256, 4)
void update_kernel(ushort* __restrict__ hio, const ushort* __restrict__ mm,
                   const ushort* __restrict__ uWiT, const float* __restrict__ ubi,
                   const ushort* __restrict__ uWoT, const float* __restrict__ ubo)
{
    constexpr int AE = 128, BM = 64, S = 256, NTW = 2, KS = 4;
    __shared__ __align__(16) ushort xs[BM * AE];
    __shared__ __align__(16) ushort ts[BM * AE];
    const int tid = threadIdx.x, lane = tid & 63, wv = tid >> 6;
    const int n0 = blockIdx.x * BM;

    for (int task = tid; task < BM * 16; task += 256) {
        int r = task >> 4, c8 = task & 15;
        int node = n0 + r;
        bf16x8 u;
        if (c8 < 8) u = *(const bf16x8*)(mm  + (size_t)node * 64 + c8 * 8);
        else        u = *(const bf16x8*)(hio + (size_t)node * 64 + (size_t)(c8 - 8) * 8);
        *(bf16x8*)((char*)xs + r * S + ((c8 * 16) ^ ((r & 7) << 4))) = u;
    }
    __syncthreads();

    const int cw0 = wv * NTW * 16;
    const int kg  = (lane >> 4) * 8;
    const int cl  = lane & 15;

    f32x4 acc[4][NTW];
    #pragma unroll
    for (int n = 0; n < NTW; n++) {
        float b = ubi[cw0 + n * 16 + cl];
        #pragma unroll
        for (int a = 0; a < 4; a++) acc[a][n] = (f32x4){b, b, b, b};
    }
    #pragma unroll
    for (int ks = 0; ks < KS; ks++) {
        bf16x8 bf[NTW];
        #pragma unroll
        for (int n = 0; n < NTW; n++)
            bf[n] = *(const bf16x8*)(uWiT + (size_t)(cw0 + n * 16 + cl) * AE + ks * 32 + kg);
        #pragma unroll
        for (int a = 0; a < 4; a++) {
            int row = a * 16 + cl;
            bf16x8 af = *(const bf16x8*)((char*)xs + row * S + (((ks * 32 + kg) * 2) ^ ((row & 7) << 4)));
            #pragma unroll
            for (int n = 0; n < NTW; n++)
                acc[a][n] = __builtin_amdgcn_mfma_f32_16x16x32_bf16(af, bf[n], acc[a][n], 0, 0, 0);
        }
    }
    #pragma unroll
    for (int a = 0; a < 4; a++)
        #pragma unroll
        for (int n = 0; n < NTW; n++)
            #pragma unroll
            for (int j = 0; j < 4; j++) {
                int row = a * 16 + (lane >> 4) * 4 + j;
                int col = cw0 + n * 16 + cl;
                *(ushort*)((char*)ts + row * S + ((col * 2) ^ ((row & 7) << 4))) = f2bf(mishf(acc[a][n][j]));
            }
    __syncthreads();

    // matmul2: 64 output cols -> 1 col-frag per wave
    f32x4 acc2[4];
    {
        float b = ubo[wv * 16 + cl];
        #pragma unroll
        for (int a = 0; a < 4; a++) acc2[a] = (f32x4){b, b, b, b};
    }
    #pragma unroll
    for (int ks = 0; ks < KS; ks++) {
        bf16x8 bf = *(const bf16x8*)(uWoT + (size_t)(wv * 16 + cl) * AE + ks * 32 + kg);
        #pragma unroll
        for (int a = 0; a < 4; a++) {
            int row = a * 16 + cl;
            bf16x8 af = *(const bf16x8*)((char*)ts + row * S + (((ks * 32 + kg) * 2) ^ ((row & 7) << 4)));
            acc2[a] = __builtin_amdgcn_mfma_f32_16x16x32_bf16(af, bf, acc2[a], 0, 0, 0);
        }
    }
    #pragma unroll
    for (int a = 0; a < 4; a++)
        #pragma unroll
        for (int j = 0; j < 4; j++) {
            int row = a * 16 + (lane >> 4) * 4 + j;
            int col = wv * 16 + cl;
            int hc = 64 + col;
            float hold = bf2f(*(ushort*)((char*)xs + row * S + ((hc * 2) ^ ((row & 7) << 4))));
            hio[(size_t)(n0 + row) * 64 + col] = f2bf(hold + acc2[a][j]);
        }
}

// ---------------------------------------------------------------------------
// Readout (parallel)
// ---------------------------------------------------------------------------
__global__ __launch_bounds__(64) void offsets_kernel(
    const int* __restrict__ toksz, int* __restrict__ off)
{
    int lane = threadIdx.x;
    int v = toksz[lane];
    int inc = v;
    #pragma unroll
    for (int o = 1; o < 64; o <<= 1) {
        int t = __shfl_up(inc, o);
        if (lane >= o) inc += t;
    }
    off[lane] = inc - v;   // exclusive
}

#define RCHUNK 32
__global__ __launch_bounds__(256) void readout_partial_kernel(
    const ushort* __restrict__ h, const int* __restrict__ toksz,
    const int* __restrict__ off, float* __restrict__ part)
{
    int s = blockIdx.x >> 5, c = blockIdx.x & (RCHUNK - 1);
    int cntr = toksz[s];
    int rpc = (cntr + RCHUNK - 1) / RCHUNK;
    int r0 = c * rpc;
    int r1 = min(r0 + rpc, cntr);
    int col = threadIdx.x & 63, rg = threadIdx.x >> 6;
    int base = off[s];
    float acc = 0.f;
    for (int r = r0 + rg; r < r1; r += 4)
        acc += bf2f(h[(size_t)(base + r) * 64 + col]);
    __shared__ float red[4][64];
    red[rg][col] = acc;
    __syncthreads();
    if (rg == 0)
        part[(size_t)blockIdx.x * 64 + col] = red[0][col] + red[1][col] + red[2][col] + red[3][col];
}

__global__ __launch_bounds__(256) void readout_reduce_kernel(
    const float* __restrict__ part, float* __restrict__ agg)
{
    int s = blockIdx.x;
    int col = threadIdx.x & 63, rg = threadIdx.x >> 6;
    float acc = 0.f;
    for (int k = rg; k < RCHUNK; k += 4)
        acc += part[(size_t)(s * RCHUNK + k) * 64 + col];
    __shared__ float red[4][64];
    red[rg][col] = acc;
    __syncthreads();
    if (rg == 0)
        agg[s * 64 + col] = red[0][col] + red[1][col] + red[2][col] + red[3][col];
}

__global__ __launch_bounds__(64) void readout_mlp_kernel(
    const float* __restrict__ agg,
    const float* __restrict__ vWi, const float* __restrict__ vbi,
    const float* __restrict__ vWo, const float* __restrict__ vbo,
    const float* __restrict__ dWi, const float* __restrict__ dbi,
    const float* __restrict__ dWo, const float* __restrict__ dbo,
    float* __restrict__ out)
{
    int s = blockIdx.x;
    int lane = threadIdx.x;
    float accv = vbi[lane], accd = dbi[lane];
    for (int k = 0; k < 64; k++) {
        float a = agg[s * 64 + k];
        accv = fmaf(a, vWi[k * 64 + lane], accv);
        accd = fmaf(a, dWi[k * 64 + lane], accd);
    }
    float pv = mishf(accv) * vWo[lane];
    float pd = mishf(accd) * dWo[lane];
    #pragma unroll
    for (int o = 1; o < 64; o <<= 1) {
        pv += __shfl_xor(pv, o);
        pd += __shfl_xor(pd, o);
    }
    if (lane == 0) { out[s] = pv + vbo[0]; out[64 + s] = pd + dbo[0]; }
}

// ---------------------------------------------------------------------------
extern "C" void kernel_launch(void* const* d_in, const int* in_sizes, int n_in,
                              void* d_out, int out_size, void* d_ws, size_t ws_size,
                              hipStream_t stream)
{
    const float* h0   = (const float*)d_in[0];
    const int* atoms1 = (const int*)d_in[1];
    const int* atoms2 = (const int*)d_in[2];
    const int* atoms3 = (const int*)d_in[3];
    const int* tsizes = (const int*)d_in[4];
    const float* Wi1 = (const float*)d_in[5],  *bi1 = (const float*)d_in[6];
    const float* Wo1 = (const float*)d_in[7],  *bo1 = (const float*)d_in[8];
    const float* Wi2 = (const float*)d_in[9],  *bi2 = (const float*)d_in[10];
    const float* Wo2 = (const float*)d_in[11], *bo2 = (const float*)d_in[12];
    const float* Wi3 = (const float*)d_in[13], *bi3 = (const float*)d_in[14];
    const float* Wo3 = (const float*)d_in[15], *bo3 = (const float*)d_in[16];
    const float* uWi = (const float*)d_in[17], *ubi = (const float*)d_in[18];
    const float* uWo = (const float*)d_in[19], *ubo = (const float*)d_in[20];
    const float* vWi = (const float*)d_in[21], *vbi = (const float*)d_in[22];
    const float* vWo = (const float*)d_in[23], *vbo = (const float*)d_in[24];
    const float* dWi = (const float*)d_in[25], *dbi = (const float*)d_in[26];
    const float* dWo = (const float*)d_in[27], *dbo = (const float*)d_in[28];
    float* out = (float*)d_out;

    const int rows1 = in_sizes[1];
    const int rows2 = in_sizes[2];
    const int rows3 = in_sizes[3];
    const int m1 = rows1, m2 = rows2 / 2, m3 = rows3 / 3;
    const int T = rows1 + rows2 + rows3;

    char* w = (char*)d_ws;
    auto alloc = [&](size_t bytes) { char* p = w; w += (bytes + 255) & ~(size_t)255; return p; };
    ushort* h1       = (ushort*)alloc(NH * 2);
    ushort* mm       = (ushort*)alloc(NH * 2);
    unsigned* cnt    = (unsigned*)alloc(N_NODES * 4);
    unsigned* base   = (unsigned*)alloc(N_NODES * 4);
    unsigned* pos    = (unsigned*)alloc(N_NODES * 4);
    unsigned* totals = (unsigned*)alloc(256 * 4);
    float* agg       = (float*)alloc(NSTATES * 64 * 4);
    float* part      = (float*)alloc((size_t)NSTATES * RCHUNK * 64 * 4);
    int* roff        = (int*)alloc(NSTATES * 4);
    ushort* WiT1 = (ushort*)alloc(64 * 64 * 2);
    ushort* WoT1 = (ushort*)alloc(64 * 64 * 2);
    ushort* WiT2 = (ushort*)alloc(128 * 128 * 2);
    ushort* WoT2 = (ushort*)alloc(128 * 128 * 2);
    ushort* WiT3 = (ushort*)alloc(192 * 192 * 2);
    ushort* WoT3 = (ushort*)alloc(192 * 192 * 2);
    ushort* uWiT = (ushort*)alloc(128 * 128 * 2);
    ushort* uWoT = (ushort*)alloc(64 * 128 * 2);
    char* tail = w;

    size_t y_bytes  = (size_t)T * 64 * 2;
    const bool csr  = ((size_t)(tail - (char*)d_ws) + ((y_bytes + 255) & ~(size_t)255)) <= ws_size;
    ushort* y_sorted = nullptr;
    unsigned* enc = nullptr;
    float* exps = nullptr;
    if (csr) {
        y_sorted = (ushort*)alloc(y_bytes);
    } else {
        enc  = (unsigned*)alloc(NH * 4);
        exps = (float*)alloc(NH * 4);
    }

    h2bf_kernel<<<(int)(NH / 8 / 256), 256, 0, stream>>>(h0, h1);

    // fused weight conversion (8 jobs)
    {
        WtJobs jobs;
        int s = 0;
        auto add = [&](int idx, const float* src, ushort* dst, int K, int Nc) {
            jobs.j[idx] = {src, dst, K, Nc, s};
            s += K * Nc;
        };
        add(0, Wi1, WiT1, 64, 64);
        add(1, Wo1, WoT1, 64, 64);
        add(2, Wi2, WiT2, 128, 128);
        add(3, Wo2, WoT2, 128, 128);
        add(4, Wi3, WiT3, 192, 192);
        add(5, Wo3, WoT3, 192, 192);
        add(6, uWi, uWiT, 128, 128);
        add(7, uWo, uWoT, 128, 64);
        jobs.total = s;
        wt_conv_all_kernel<<<(s + 255) / 256, 256, 0, stream>>>(jobs);
    }

    if (csr) {
        hipMemsetAsync(cnt, 0, N_NODES * 4, stream);
        count_kernel<<<(rows1 + 255) / 256, 256, 0, stream>>>(atoms1, rows1, cnt);
        count_kernel<<<(rows2 + 255) / 256, 256, 0, stream>>>(atoms2, rows2, cnt);
        count_kernel<<<(rows3 + 255) / 256, 256, 0, stream>>>(atoms3, rows3, cnt);
        scan1_kernel<<<256, 256, 0, stream>>>(cnt, base, totals);
        scan2_kernel<<<256, 256, 0, stream>>>(base, pos, totals);
    }

    const int g1 = (m1 + 63) / 64, g2 = (m2 + 63) / 64, g3 = (m3 + 63) / 64;

    for (int layer = 0; layer < 2; layer++) {
        if (csr) {
            rel_kernel<1, 0><<<g1, 256, 0, stream>>>(h1, atoms1, WiT1, bi1, WoT1, bo1, pos, y_sorted, nullptr, nullptr, m1);
            rel_kernel<2, 0><<<g2, 256, 0, stream>>>(h1, atoms2, WiT2, bi2, WoT2, bo2, pos, y_sorted, nullptr, nullptr, m2);
            rel_kernel<3, 0><<<g3, 256, 0, stream>>>(h1, atoms3, WiT3, bi3, WoT3, bo3, pos, y_sorted, nullptr, nullptr, m3);
            aggregate_kernel<<<N_NODES / 4, 256, 0, stream>>>(y_sorted, base, cnt, pos, mm);
        } else {
            hipMemsetAsync(enc, 0, NH * 8, stream);   // enc + exps
            rel_kernel<1, 1><<<g1, 256, 0, stream>>>(h1, atoms1, WiT1, bi1, WoT1, bo1, nullptr, nullptr, enc, exps, m1);
            rel_kernel<2, 1><<<g2, 256, 0, stream>>>(h1, atoms2, WiT2, bi2, WoT2, bo2, nullptr, nullptr, enc, exps, m2);
            rel_kernel<3, 1><<<g3, 256, 0, stream>>>(h1, atoms3, WiT3, bi3, WoT3, bo3, nullptr, nullptr, enc, exps, m3);
            rel_kernel<1, 2><<<g1, 256, 0, stream>>>(h1, atoms1, WiT1, bi1, WoT1, bo1, nullptr, nullptr, enc, exps, m1);
            rel_kernel<2, 2><<<g2, 256, 0, stream>>>(h1, atoms2, WiT2, bi2, WoT2, bo2, nullptr, nullptr, enc, exps, m2);
            rel_kernel<3, 2><<<g3, 256, 0, stream>>>(h1, atoms3, WiT3, bi3, WoT3, bo3, nullptr, nullptr, enc, exps, m3);
            finalize_mm_kernel<<<(int)((NH + 255) / 256), 256, 0, stream>>>(enc, exps, mm);
        }
        update_kernel<<<N_NODES / 64, 256, 0, stream>>>(h1, mm, uWiT, ubi, uWoT, ubo);
    }

    offsets_kernel<<<1, 64, 0, stream>>>(tsizes, roff);
    readout_partial_kernel<<<NSTATES * RCHUNK, 256, 0, stream>>>(h1, tsizes, roff, part);
    readout_reduce_kernel<<<NSTATES, 256, 0, stream>>>(part, agg);
    readout_mlp_kernel<<<NSTATES, 64, 0, stream>>>(agg, vWi, vbi, vWo, vbo,
                                                   dWi, dbi, dWo, dbo, out);
}

// Round 7
// 695.274 us; speedup vs baseline: 14.9817x; 1.1930x over previous
//
#include <hip/hip_runtime.h>
#include <math.h>

#define N_NODES 131072
#define NSTATES 64
#define NH ((size_t)N_NODES * 64)

typedef short bf16x8 __attribute__((ext_vector_type(8)));
typedef float f32x4 __attribute__((ext_vector_type(4)));

__device__ __forceinline__ ushort f2bf(float f) {
    unsigned u = __float_as_uint(f);
    return (ushort)((u + 0x7fffu + ((u >> 16) & 1u)) >> 16);
}
__device__ __forceinline__ float bf2f(ushort h) {
    return __uint_as_float(((unsigned)h) << 16);
}
// mish(x) = x*tanh(softplus(x)) = x*(t^2+2t)/(t^2+2t+2), t=e^x
__device__ __forceinline__ float mishf(float x) {
    if (x > 30.f) return x;
    float t = __builtin_amdgcn_exp2f(1.4426950408889634f * x);
    float r = t * t + 2.f * t;
    return x * r * __builtin_amdgcn_rcpf(r + 2.f);
}
// order-preserving f32 -> u32 (0 only for -NaN => "empty" sentinel)
__device__ __forceinline__ unsigned enc_f(float f) {
    unsigned u = __float_as_uint(f);
    return (u & 0x80000000u) ? ~u : (u | 0x80000000u);
}
__device__ __forceinline__ float dec_f(unsigned k) {
    unsigned u = (k & 0x80000000u) ? (k & 0x7fffffffu) : ~k;
    return __uint_as_float(u);
}

__device__ __forceinline__ bf16x8 load8f(const float* p) {
    const float4* q = (const float4*)p;
    float4 v0 = q[0], v1 = q[1];
    bf16x8 u;
    u[0] = (short)f2bf(v0.x); u[1] = (short)f2bf(v0.y);
    u[2] = (short)f2bf(v0.z); u[3] = (short)f2bf(v0.w);
    u[4] = (short)f2bf(v1.x); u[5] = (short)f2bf(v1.y);
    u[6] = (short)f2bf(v1.z); u[7] = (short)f2bf(v1.w);
    return u;
}

// ---------------------------------------------------------------------------
// h f32 -> bf16
// ---------------------------------------------------------------------------
__global__ __launch_bounds__(256) void h2bf_kernel(
    const float* __restrict__ h, ushort* __restrict__ hb)
{
    size_t i = ((size_t)blockIdx.x * 256 + threadIdx.x) * 8;
    if (i >= NH) return;
    *(bf16x8*)(hb + i) = load8f(h + i);
}

// ---------------------------------------------------------------------------
// fused weight convert: 8 jobs, W [K][Nc] f32 -> WT [Nc][K] bf16
// ---------------------------------------------------------------------------
struct WtJob  { const float* src; ushort* dst; int K; int Nc; int start; };
struct WtJobs { WtJob j[8]; int total; };

__global__ __launch_bounds__(256) void wt_conv_all_kernel(WtJobs jobs)
{
    int i = blockIdx.x * 256 + threadIdx.x;
    if (i >= jobs.total) return;
    int jj = 0;
    #pragma unroll
    for (int k = 1; k < 8; k++) if (i >= jobs.j[k].start) jj = k;
    WtJob jb = jobs.j[jj];
    int local = i - jb.start;
    int o = local / jb.K, k = local % jb.K;
    jb.dst[(size_t)o * jb.K + k] = f2bf(jb.src[(size_t)k * jb.Nc + o]);
}

// ---------------------------------------------------------------------------
// CSR build
// ---------------------------------------------------------------------------
__global__ __launch_bounds__(256) void count_kernel(
    const int* __restrict__ atoms, int T, unsigned* __restrict__ cnt)
{
    int i = blockIdx.x * 256 + threadIdx.x;
    if (i < T) atomicAdd(&cnt[atoms[i]], 1u);
}

__global__ __launch_bounds__(256) void scan1_kernel(
    const unsigned* __restrict__ cnt, unsigned* __restrict__ base,
    unsigned* __restrict__ totals)
{
    __shared__ unsigned sm[256];
    int t = threadIdx.x, blk = blockIdx.x;
    int i0 = blk * 512;
    unsigned a = cnt[i0 + 2 * t], bb = cnt[i0 + 2 * t + 1];
    unsigned p = a + bb;
    sm[t] = p;
    __syncthreads();
    for (int off = 1; off < 256; off <<= 1) {
        unsigned v = (t >= off) ? sm[t - off] : 0u;
        __syncthreads();
        sm[t] += v;
        __syncthreads();
    }
    unsigned incl = sm[t];
    base[i0 + 2 * t]     = incl - p;
    base[i0 + 2 * t + 1] = incl - p + a;
    if (t == 255) totals[blk] = sm[255];
}

// also seeds pos = base (replaces copy_pos for layer 0)
__global__ __launch_bounds__(256) void scan2_kernel(
    unsigned* __restrict__ base, unsigned* __restrict__ pos,
    const unsigned* __restrict__ totals)
{
    __shared__ unsigned ps[4];
    int t = threadIdx.x, blk = blockIdx.x;
    int lane = t & 63, wv = t >> 6;
    unsigned v = (t < blk) ? totals[t] : 0u;
    #pragma unroll
    for (int o = 32; o >= 1; o >>= 1) v += (unsigned)__shfl_xor((int)v, o);
    if (lane == 0) ps[wv] = v;
    __syncthreads();
    unsigned off = ps[0] + ps[1] + ps[2] + ps[3];
    int i0 = blk * 512;
    unsigned b0 = base[i0 + 2 * t] + off;
    unsigned b1 = base[i0 + 2 * t + 1] + off;
    base[i0 + 2 * t]     = b0;  pos[i0 + 2 * t]     = b0;
    base[i0 + 2 * t + 1] = b1;  pos[i0 + 2 * t + 1] = b1;
}

// ---------------------------------------------------------------------------
// Relation MLP (bf16 MFMA, column-split waves):
//   y = x + mish(x@Wi+bi)@Wo+bo
// MODE 0: scatter rows to CSR slots (parallel slot atomics)
// MODE 1: atomicMax enc        (fallback pass 1)
// MODE 2: atomicAdd exp-sum    (fallback pass 2)
// ---------------------------------------------------------------------------
template<int ARITY, int MODE>
__global__ __launch_bounds__(256, (ARITY == 3) ? 3 : 4)
void rel_kernel(const ushort* __restrict__ h, const int* __restrict__ atoms,
                const ushort* __restrict__ WiT, const float* __restrict__ bi,
                const ushort* __restrict__ WoT, const float* __restrict__ bo,
                unsigned* __restrict__ pos, ushort* __restrict__ y_sorted,
                unsigned* __restrict__ enc, float* __restrict__ exps, int m)
{
    constexpr int AE  = ARITY * 64;
    constexpr int BM  = 64;
    constexpr int NTW = AE / 64;            // 16-col frags per wave
    constexpr int KS  = AE / 32;            // K steps
    constexpr int S   = AE * 2;             // LDS row stride bytes
    __shared__ __align__(16) ushort xs[BM * AE];
    __shared__ __align__(16) ushort ts[BM * AE];
    __shared__ unsigned slot_sm[BM * ARITY];
    const int tid = threadIdx.x, lane = tid & 63, wv = tid >> 6;
    const int a0 = blockIdx.x * BM;

    // ---- stage gathered x rows (bf16, XOR-swizzled) ----
    for (int task = tid; task < BM * (AE / 8); task += 256) {
        int r  = task / (AE / 8);
        int c8 = task % (AE / 8);
        int atom = a0 + r;
        bf16x8 u = {0, 0, 0, 0, 0, 0, 0, 0};
        if (atom < m) {
            int node = atoms[atom * ARITY + (c8 >> 3)];
            u = *(const bf16x8*)(h + (size_t)node * 64 + (size_t)(c8 & 7) * 8);
        }
        *(bf16x8*)((char*)xs + r * S + ((c8 * 16) ^ ((r & 7) << 4))) = u;
    }
    __syncthreads();

    const int cw0 = wv * NTW * 16;          // wave's first output column
    const int kg  = (lane >> 4) * 8;
    const int cl  = lane & 15;

    // ---- matmul1: inner = x @ Wi + bi ----
    f32x4 acc[4][NTW];
    #pragma unroll
    for (int n = 0; n < NTW; n++) {
        float b = bi[cw0 + n * 16 + cl];
        #pragma unroll
        for (int a = 0; a < 4; a++) acc[a][n] = (f32x4){b, b, b, b};
    }
    #pragma unroll
    for (int ks = 0; ks < KS; ks++) {
        bf16x8 bf[NTW];
        #pragma unroll
        for (int n = 0; n < NTW; n++)
            bf[n] = *(const bf16x8*)(WiT + (size_t)(cw0 + n * 16 + cl) * AE + ks * 32 + kg);
        #pragma unroll
        for (int a = 0; a < 4; a++) {
            int row = a * 16 + cl;
            bf16x8 af = *(const bf16x8*)((char*)xs + row * S + (((ks * 32 + kg) * 2) ^ ((row & 7) << 4)));
            #pragma unroll
            for (int n = 0; n < NTW; n++)
                acc[a][n] = __builtin_amdgcn_mfma_f32_16x16x32_bf16(af, bf[n], acc[a][n], 0, 0, 0);
        }
    }
    // D layout: row=(lane>>4)*4+j, col=lane&15  (m89-verified)
    #pragma unroll
    for (int a = 0; a < 4; a++)
        #pragma unroll
        for (int n = 0; n < NTW; n++)
            #pragma unroll
            for (int j = 0; j < 4; j++) {
                int row = a * 16 + (lane >> 4) * 4 + j;
                int col = cw0 + n * 16 + cl;
                *(ushort*)((char*)ts + row * S + ((col * 2) ^ ((row & 7) << 4))) = f2bf(mishf(acc[a][n][j]));
            }
    __syncthreads();

    // ---- matmul2: out = t @ Wo + bo ----
    #pragma unroll
    for (int n = 0; n < NTW; n++) {
        float b = bo[cw0 + n * 16 + cl];
        #pragma unroll
        for (int a = 0; a < 4; a++) acc[a][n] = (f32x4){b, b, b, b};
    }
    #pragma unroll
    for (int ks = 0; ks < KS; ks++) {
        bf16x8 bf[NTW];
        #pragma unroll
        for (int n = 0; n < NTW; n++)
            bf[n] = *(const bf16x8*)(WoT + (size_t)(cw0 + n * 16 + cl) * AE + ks * 32 + kg);
        #pragma unroll
        for (int a = 0; a < 4; a++) {
            int row = a * 16 + cl;
            bf16x8 af = *(const bf16x8*)((char*)ts + row * S + (((ks * 32 + kg) * 2) ^ ((row & 7) << 4)));
            #pragma unroll
            for (int n = 0; n < NTW; n++)
                acc[a][n] = __builtin_amdgcn_mfma_f32_16x16x32_bf16(af, bf[n], acc[a][n], 0, 0, 0);
        }
    }
    // residual y = x + out -> back into xs (bf16)
    #pragma unroll
    for (int a = 0; a < 4; a++)
        #pragma unroll
        for (int n = 0; n < NTW; n++)
            #pragma unroll
            for (int j = 0; j < 4; j++) {
                int row = a * 16 + (lane >> 4) * 4 + j;
                int col = cw0 + n * 16 + cl;
                ushort* xp = (ushort*)((char*)xs + row * S + ((col * 2) ^ ((row & 7) << 4)));
                *xp = f2bf(bf2f(*xp) + acc[a][n][j]);
            }
    __syncthreads();

    // ---- epilogue ----
    const int nrows = BM * ARITY;
    if (MODE == 0) {
        // parallel slot acquisition: one thread per message row
        if (tid < nrows) {
            int grow = a0 * ARITY + tid;
            unsigned s = 0u;
            if (grow < m * ARITY) s = atomicAdd(&pos[atoms[grow]], 1u);
            slot_sm[tid] = s;
        }
        __syncthreads();
        for (int rr = wv; rr < nrows; rr += 4) {
            int grow = a0 * ARITY + rr;
            if (grow >= m * ARITY) break;
            int r = rr / ARITY, c = (rr % ARITY) * 64 + lane;
            ushort yu = *(ushort*)((char*)xs + r * S + ((c * 2) ^ ((r & 7) << 4)));
            y_sorted[(size_t)slot_sm[rr] * 64 + lane] = yu;
        }
    } else {
        for (int rr = wv; rr < nrows; rr += 4) {
            int grow = a0 * ARITY + rr;
            if (grow >= m * ARITY) break;
            int node = atoms[grow];
            int r = rr / ARITY, c = (rr % ARITY) * 64 + lane;
            ushort yu = *(ushort*)((char*)xs + r * S + ((c * 2) ^ ((r & 7) << 4)));
            if (MODE == 1) {
                atomicMax(&enc[(size_t)node * 64 + lane], enc_f(bf2f(yu)));
            } else {
                size_t cell = (size_t)node * 64 + lane;
                float mx = dec_f(enc[cell]);
                atomicAdd(&exps[cell], __builtin_amdgcn_exp2f(17.312340490667562f * (bf2f(yu) - mx)));
            }
        }
    }
}

// ---------------------------------------------------------------------------
// Per-node smooth-max over CSR-sorted messages (no atomics).
// Same addressing as the round-5 passing version (lane = column, scalar 2B
// loads); single-pass ONLINE max/exp-sum, 4x unrolled for load ILP.
// Side effect: pos[node] = base[node] (re-seeds pos for the next layer).
// ---------------------------------------------------------------------------
#define KSM 17.312340490667562f
__global__ __launch_bounds__(256) void aggregate_kernel(
    const ushort* __restrict__ y_sorted, const unsigned* __restrict__ base,
    const unsigned* __restrict__ cnt, unsigned* __restrict__ pos,
    ushort* __restrict__ mm)
{
    int node = blockIdx.x * 4 + (threadIdx.x >> 6);
    int lane = threadIdx.x & 63;
    unsigned b = base[node], c = cnt[node];
    if (lane == 0) pos[node] = b;
    const ushort* p = y_sorted + (size_t)b * 64 + lane;

    float m = -3.402823466e38f;
    float s = 0.f;
    unsigned j = 0;
    for (; j + 4 <= c; j += 4) {
        float a0 = bf2f(p[(size_t)(j + 0) * 64]);
        float a1 = bf2f(p[(size_t)(j + 1) * 64]);
        float a2 = bf2f(p[(size_t)(j + 2) * 64]);
        float a3 = bf2f(p[(size_t)(j + 3) * 64]);
        float q  = fmaxf(fmaxf(a0, a1), fmaxf(a2, a3));
        float mn = fmaxf(m, q);
        s = s * __builtin_amdgcn_exp2f(KSM * (m - mn))
          + __builtin_amdgcn_exp2f(KSM * (a0 - mn))
          + __builtin_amdgcn_exp2f(KSM * (a1 - mn))
          + __builtin_amdgcn_exp2f(KSM * (a2 - mn))
          + __builtin_amdgcn_exp2f(KSM * (a3 - mn));
        m = mn;
    }
    for (; j < c; j++) {
        float a  = bf2f(p[(size_t)j * 64]);
        float mn = fmaxf(m, a);
        s = s * __builtin_amdgcn_exp2f(KSM * (m - mn))
          + __builtin_amdgcn_exp2f(KSM * (a - mn));
        m = mn;
    }
    float me = c ? m : 0.f;
    float r = __builtin_amdgcn_logf(1e-16f + s) * 0.05776226504666211f + me;
    mm[(size_t)node * 64 + lane] = f2bf(r);
}

// fallback finalize: mm from (enc, exps)
__global__ __launch_bounds__(256) void finalize_mm_kernel(
    const unsigned* __restrict__ enc, const float* __restrict__ exps,
    ushort* __restrict__ mm)
{
    size_t i = (size_t)blockIdx.x * 256 + threadIdx.x;
    if (i >= NH) return;
    unsigned key = enc[i];
    float mx = key ? dec_f(key) : 0.f;
    float r = __builtin_amdgcn_logf(1e-16f + exps[i]) * 0.05776226504666211f + mx;
    mm[i] = f2bf(r);
}

// ---------------------------------------------------------------------------
// Node update (bf16 MFMA, in-place): h = h + mish([mm,h]@uWi+ubi)@uWo+ubo
// ---------------------------------------------------------------------------
__global__ __launch_bounds__(256, 4)
void update_kernel(ushort* __restrict__ hio, const ushort* __restrict__ mm,
                   const ushort* __restrict__ uWiT, const float* __restrict__ ubi,
                   const ushort* __restrict__ uWoT, const float* __restrict__ ubo)
{
    constexpr int AE = 128, BM = 64, S = 256, NTW = 2, KS = 4;
    __shared__ __align__(16) ushort xs[BM * AE];
    __shared__ __align__(16) ushort ts[BM * AE];
    const int tid = threadIdx.x, lane = tid & 63, wv = tid >> 6;
    const int n0 = blockIdx.x * BM;

    for (int task = tid; task < BM * 16; task += 256) {
        int r = task >> 4, c8 = task & 15;
        int node = n0 + r;
        bf16x8 u;
        if (c8 < 8) u = *(const bf16x8*)(mm  + (size_t)node * 64 + c8 * 8);
        else        u = *(const bf16x8*)(hio + (size_t)node * 64 + (size_t)(c8 - 8) * 8);
        *(bf16x8*)((char*)xs + r * S + ((c8 * 16) ^ ((r & 7) << 4))) = u;
    }
    __syncthreads();

    const int cw0 = wv * NTW * 16;
    const int kg  = (lane >> 4) * 8;
    const int cl  = lane & 15;

    f32x4 acc[4][NTW];
    #pragma unroll
    for (int n = 0; n < NTW; n++) {
        float b = ubi[cw0 + n * 16 + cl];
        #pragma unroll
        for (int a = 0; a < 4; a++) acc[a][n] = (f32x4){b, b, b, b};
    }
    #pragma unroll
    for (int ks = 0; ks < KS; ks++) {
        bf16x8 bf[NTW];
        #pragma unroll
        for (int n = 0; n < NTW; n++)
            bf[n] = *(const bf16x8*)(uWiT + (size_t)(cw0 + n * 16 + cl) * AE + ks * 32 + kg);
        #pragma unroll
        for (int a = 0; a < 4; a++) {
            int row = a * 16 + cl;
            bf16x8 af = *(const bf16x8*)((char*)xs + row * S + (((ks * 32 + kg) * 2) ^ ((row & 7) << 4)));
            #pragma unroll
            for (int n = 0; n < NTW; n++)
                acc[a][n] = __builtin_amdgcn_mfma_f32_16x16x32_bf16(af, bf[n], acc[a][n], 0, 0, 0);
        }
    }
    #pragma unroll
    for (int a = 0; a < 4; a++)
        #pragma unroll
        for (int n = 0; n < NTW; n++)
            #pragma unroll
            for (int j = 0; j < 4; j++) {
                int row = a * 16 + (lane >> 4) * 4 + j;
                int col = cw0 + n * 16 + cl;
                *(ushort*)((char*)ts + row * S + ((col * 2) ^ ((row & 7) << 4))) = f2bf(mishf(acc[a][n][j]));
            }
    __syncthreads();

    // matmul2: 64 output cols -> 1 col-frag per wave
    f32x4 acc2[4];
    {
        float b = ubo[wv * 16 + cl];
        #pragma unroll
        for (int a = 0; a < 4; a++) acc2[a] = (f32x4){b, b, b, b};
    }
    #pragma unroll
    for (int ks = 0; ks < KS; ks++) {
        bf16x8 bf = *(const bf16x8*)(uWoT + (size_t)(wv * 16 + cl) * AE + ks * 32 + kg);
        #pragma unroll
        for (int a = 0; a < 4; a++) {
            int row = a * 16 + cl;
            bf16x8 af = *(const bf16x8*)((char*)ts + row * S + (((ks * 32 + kg) * 2) ^ ((row & 7) << 4)));
            acc2[a] = __builtin_amdgcn_mfma_f32_16x16x32_bf16(af, bf, acc2[a], 0, 0, 0);
        }
    }
    #pragma unroll
    for (int a = 0; a < 4; a++)
        #pragma unroll
        for (int j = 0; j < 4; j++) {
            int row = a * 16 + (lane >> 4) * 4 + j;
            int col = wv * 16 + cl;
            int hc = 64 + col;
            float hold = bf2f(*(ushort*)((char*)xs + row * S + ((hc * 2) ^ ((row & 7) << 4))));
            hio[(size_t)(n0 + row) * 64 + col] = f2bf(hold + acc2[a][j]);
        }
}

// ---------------------------------------------------------------------------
// Readout (parallel)
// ---------------------------------------------------------------------------
__global__ __launch_bounds__(64) void offsets_kernel(
    const int* __restrict__ toksz, int* __restrict__ off)
{
    int lane = threadIdx.x;
    int v = toksz[lane];
    int inc = v;
    #pragma unroll
    for (int o = 1; o < 64; o <<= 1) {
        int t = __shfl_up(inc, o);
        if (lane >= o) inc += t;
    }
    off[lane] = inc - v;   // exclusive
}

#define RCHUNK 32
__global__ __launch_bounds__(256) void readout_partial_kernel(
    const ushort* __restrict__ h, const int* __restrict__ toksz,
    const int* __restrict__ off, float* __restrict__ part)
{
    int s = blockIdx.x >> 5, c = blockIdx.x & (RCHUNK - 1);
    int cntr = toksz[s];
    int rpc = (cntr + RCHUNK - 1) / RCHUNK;
    int r0 = c * rpc;
    int r1 = min(r0 + rpc, cntr);
    int col = threadIdx.x & 63, rg = threadIdx.x >> 6;
    int base = off[s];
    float acc = 0.f;
    for (int r = r0 + rg; r < r1; r += 4)
        acc += bf2f(h[(size_t)(base + r) * 64 + col]);
    __shared__ float red[4][64];
    red[rg][col] = acc;
    __syncthreads();
    if (rg == 0)
        part[(size_t)blockIdx.x * 64 + col] = red[0][col] + red[1][col] + red[2][col] + red[3][col];
}

__global__ __launch_bounds__(256) void readout_reduce_kernel(
    const float* __restrict__ part, float* __restrict__ agg)
{
    int s = blockIdx.x;
    int col = threadIdx.x & 63, rg = threadIdx.x >> 6;
    float acc = 0.f;
    for (int k = rg; k < RCHUNK; k += 4)
        acc += part[(size_t)(s * RCHUNK + k) * 64 + col];
    __shared__ float red[4][64];
    red[rg][col] = acc;
    __syncthreads();
    if (rg == 0)
        agg[s * 64 + col] = red[0][col] + red[1][col] + red[2][col] + red[3][col];
}

__global__ __launch_bounds__(64) void readout_mlp_kernel(
    const float* __restrict__ agg,
    const float* __restrict__ vWi, const float* __restrict__ vbi,
    const float* __restrict__ vWo, const float* __restrict__ vbo,
    const float* __restrict__ dWi, const float* __restrict__ dbi,
    const float* __restrict__ dWo, const float* __restrict__ dbo,
    float* __restrict__ out)
{
    int s = blockIdx.x;
    int lane = threadIdx.x;
    float accv = vbi[lane], accd = dbi[lane];
    for (int k = 0; k < 64; k++) {
        float a = agg[s * 64 + k];
        accv = fmaf(a, vWi[k * 64 + lane], accv);
        accd = fmaf(a, dWi[k * 64 + lane], accd);
    }
    float pv = mishf(accv) * vWo[lane];
    float pd = mishf(accd) * dWo[lane];
    #pragma unroll
    for (int o = 1; o < 64; o <<= 1) {
        pv += __shfl_xor(pv, o);
        pd += __shfl_xor(pd, o);
    }
    if (lane == 0) { out[s] = pv + vbo[0]; out[64 + s] = pd + dbo[0]; }
}

// ---------------------------------------------------------------------------
extern "C" void kernel_launch(void* const* d_in, const int* in_sizes, int n_in,
                              void* d_out, int out_size, void* d_ws, size_t ws_size,
                              hipStream_t stream)
{
    const float* h0   = (const float*)d_in[0];
    const int* atoms1 = (const int*)d_in[1];
    const int* atoms2 = (const int*)d_in[2];
    const int* atoms3 = (const int*)d_in[3];
    const int* tsizes = (const int*)d_in[4];
    const float* Wi1 = (const float*)d_in[5],  *bi1 = (const float*)d_in[6];
    const float* Wo1 = (const float*)d_in[7],  *bo1 = (const float*)d_in[8];
    const float* Wi2 = (const float*)d_in[9],  *bi2 = (const float*)d_in[10];
    const float* Wo2 = (const float*)d_in[11], *bo2 = (const float*)d_in[12];
    const float* Wi3 = (const float*)d_in[13], *bi3 = (const float*)d_in[14];
    const float* Wo3 = (const float*)d_in[15], *bo3 = (const float*)d_in[16];
    const float* uWi = (const float*)d_in[17], *ubi = (const float*)d_in[18];
    const float* uWo = (const float*)d_in[19], *ubo = (const float*)d_in[20];
    const float* vWi = (const float*)d_in[21], *vbi = (const float*)d_in[22];
    const float* vWo = (const float*)d_in[23], *vbo = (const float*)d_in[24];
    const float* dWi = (const float*)d_in[25], *dbi = (const float*)d_in[26];
    const float* dWo = (const float*)d_in[27], *dbo = (const float*)d_in[28];
    float* out = (float*)d_out;

    const int rows1 = in_sizes[1];
    const int rows2 = in_sizes[2];
    const int rows3 = in_sizes[3];
    const int m1 = rows1, m2 = rows2 / 2, m3 = rows3 / 3;
    const int T = rows1 + rows2 + rows3;

    char* w = (char*)d_ws;
    auto alloc = [&](size_t bytes) { char* p = w; w += (bytes + 255) & ~(size_t)255; return p; };
    ushort* h1       = (ushort*)alloc(NH * 2);
    ushort* mm       = (ushort*)alloc(NH * 2);
    unsigned* cnt    = (unsigned*)alloc(N_NODES * 4);
    unsigned* base   = (unsigned*)alloc(N_NODES * 4);
    unsigned* pos    = (unsigned*)alloc(N_NODES * 4);
    unsigned* totals = (unsigned*)alloc(256 * 4);
    float* agg       = (float*)alloc(NSTATES * 64 * 4);
    float* part      = (float*)alloc((size_t)NSTATES * RCHUNK * 64 * 4);
    int* roff        = (int*)alloc(NSTATES * 4);
    ushort* WiT1 = (ushort*)alloc(64 * 64 * 2);
    ushort* WoT1 = (ushort*)alloc(64 * 64 * 2);
    ushort* WiT2 = (ushort*)alloc(128 * 128 * 2);
    ushort* WoT2 = (ushort*)alloc(128 * 128 * 2);
    ushort* WiT3 = (ushort*)alloc(192 * 192 * 2);
    ushort* WoT3 = (ushort*)alloc(192 * 192 * 2);
    ushort* uWiT = (ushort*)alloc(128 * 128 * 2);
    ushort* uWoT = (ushort*)alloc(64 * 128 * 2);
    char* tail = w;

    size_t y_bytes  = (size_t)T * 64 * 2;
    const bool csr  = ((size_t)(tail - (char*)d_ws) + ((y_bytes + 255) & ~(size_t)255)) <= ws_size;
    ushort* y_sorted = nullptr;
    unsigned* enc = nullptr;
    float* exps = nullptr;
    if (csr) {
        y_sorted = (ushort*)alloc(y_bytes);
    } else {
        enc  = (unsigned*)alloc(NH * 4);
        exps = (float*)alloc(NH * 4);
    }

    h2bf_kernel<<<(int)(NH / 8 / 256), 256, 0, stream>>>(h0, h1);

    // fused weight conversion (8 jobs)
    {
        WtJobs jobs;
        int s = 0;
        auto add = [&](int idx, const float* src, ushort* dst, int K, int Nc) {
            jobs.j[idx] = {src, dst, K, Nc, s};
            s += K * Nc;
        };
        add(0, Wi1, WiT1, 64, 64);
        add(1, Wo1, WoT1, 64, 64);
        add(2, Wi2, WiT2, 128, 128);
        add(3, Wo2, WoT2, 128, 128);
        add(4, Wi3, WiT3, 192, 192);
        add(5, Wo3, WoT3, 192, 192);
        add(6, uWi, uWiT, 128, 128);
        add(7, uWo, uWoT, 128, 64);
        jobs.total = s;
        wt_conv_all_kernel<<<(s + 255) / 256, 256, 0, stream>>>(jobs);
    }

    if (csr) {
        hipMemsetAsync(cnt, 0, N_NODES * 4, stream);
        count_kernel<<<(rows1 + 255) / 256, 256, 0, stream>>>(atoms1, rows1, cnt);
        count_kernel<<<(rows2 + 255) / 256, 256, 0, stream>>>(atoms2, rows2, cnt);
        count_kernel<<<(rows3 + 255) / 256, 256, 0, stream>>>(atoms3, rows3, cnt);
        scan1_kernel<<<256, 256, 0, stream>>>(cnt, base, totals);
        scan2_kernel<<<256, 256, 0, stream>>>(base, pos, totals);
    }

    const int g1 = (m1 + 63) / 64, g2 = (m2 + 63) / 64, g3 = (m3 + 63) / 64;

    for (int layer = 0; layer < 2; layer++) {
        if (csr) {
            rel_kernel<1, 0><<<g1, 256, 0, stream>>>(h1, atoms1, WiT1, bi1, WoT1, bo1, pos, y_sorted, nullptr, nullptr, m1);
            rel_kernel<2, 0><<<g2, 256, 0, stream>>>(h1, atoms2, WiT2, bi2, WoT2, bo2, pos, y_sorted, nullptr, nullptr, m2);
            rel_kernel<3, 0><<<g3, 256, 0, stream>>>(h1, atoms3, WiT3, bi3, WoT3, bo3, pos, y_sorted, nullptr, nullptr, m3);
            aggregate_kernel<<<N_NODES / 4, 256, 0, stream>>>(y_sorted, base, cnt, pos, mm);
        } else {
            hipMemsetAsync(enc, 0, NH * 8, stream);   // enc + exps
            rel_kernel<1, 1><<<g1, 256, 0, stream>>>(h1, atoms1, WiT1, bi1, WoT1, bo1, nullptr, nullptr, enc, exps, m1);
            rel_kernel<2, 1><<<g2, 256, 0, stream>>>(h1, atoms2, WiT2, bi2, WoT2, bo2, nullptr, nullptr, enc, exps, m2);
            rel_kernel<3, 1><<<g3, 256, 0, stream>>>(h1, atoms3, WiT3, bi3, WoT3, bo3, nullptr, nullptr, enc, exps, m3);
            rel_kernel<1, 2><<<g1, 256, 0, stream>>>(h1, atoms1, WiT1, bi1, WoT1, bo1, nullptr, nullptr, enc, exps, m1);
            rel_kernel<2, 2><<<g2, 256, 0, stream>>>(h1, atoms2, WiT2, bi2, WoT2, bo2, nullptr, nullptr, enc, exps, m2);
            rel_kernel<3, 2><<<g3, 256, 0, stream>>>(h1, atoms3, WiT3, bi3, WoT3, bo3, nullptr, nullptr, enc, exps, m3);
            finalize_mm_kernel<<<(int)((NH + 255) / 256), 256, 0, stream>>>(enc, exps, mm);
        }
        update_kernel<<<N_NODES / 64, 256, 0, stream>>>(h1, mm, uWiT, ubi, uWoT, ubo);
    }

    offsets_kernel<<<1, 64, 0, stream>>>(tsizes, roff);
    readout_partial_kernel<<<NSTATES * RCHUNK, 256, 0, stream>>>(h1, tsizes, roff, part);
    readout_reduce_kernel<<<NSTATES, 256, 0, stream>>>(part, agg);
    readout_mlp_kernel<<<NSTATES, 64, 0, stream>>>(agg, vWi, vbi, vWo, vbo,
                                                   dWi, dbi, dWo, dbo, out);
}